// Round 1
// baseline (333.766 us; speedup 1.0000x reference)
//
#include <hip/hip_runtime.h>
#include <hip/hip_bf16.h>
#include <stdint.h>

// MoE grouped linear: y[t] = relu(x[t] @ W[idxs[t]] + b[idxs[t]])
// T=16384, D_IN=D_OUT=1024, E=8.
// Pipeline: detect dtype -> bucket tokens by expert -> transpose W to bf16 [E][n][k]
// -> gather-GEMM (m97 structure: 128x128 tile, BK=32, 16x16x32 bf16 MFMA,
//    global_load_lds 16B staging) -> bias+relu+scatter store.

#define T_TOK 16384
#define DIN   1024
#define DOUT  1024
#define NE    8
#define BM    128
#define BN    128
#define BK    32

typedef __hip_bfloat16 bf16;
typedef __attribute__((ext_vector_type(8))) short short8;
typedef __attribute__((ext_vector_type(4))) float floatx4;

__device__ __forceinline__ short f2b(float f) {
  return __builtin_bit_cast(short, __float2bfloat16(f));
}
__device__ __forceinline__ float b2f(unsigned short u) {
  unsigned v = ((unsigned)u) << 16;
  return __builtin_bit_cast(float, v);
}
__device__ __forceinline__ void glds16(const void* g, void* l) {
  __builtin_amdgcn_global_load_lds(
      (__attribute__((address_space(1))) void*)g,
      (__attribute__((address_space(3))) void*)l, 16, 0, 0);
}

// ---- dtype detect: bf16 N(0,1) data never has exponent >= 0xC0; fp32 data
// reinterpreted as ushorts has uniform-random exponents in the low halves.
__global__ void k_detect(const unsigned short* __restrict__ x, int* __restrict__ flag) {
  if (threadIdx.x == 0) {
    int f = 0;
    for (int i = 0; i < 256; ++i) {
      int ex = (x[i] >> 7) & 0xFF;
      if (ex >= 0xC0) f = 1;
    }
    *flag = f;  // 1 => underlying data is fp32
  }
}

__global__ void k_zero(int* __restrict__ counts, int* __restrict__ cursor) {
  int t = threadIdx.x;
  if (t < NE) { counts[t] = 0; cursor[t] = 0; }
}

__global__ void k_hist(const int* __restrict__ idxs, int* __restrict__ counts) {
  __shared__ int lc[NE];
  if (threadIdx.x < NE) lc[threadIdx.x] = 0;
  __syncthreads();
  int t = blockIdx.x * 256 + threadIdx.x;
  atomicAdd(&lc[idxs[t]], 1);
  __syncthreads();
  if (threadIdx.x < NE) atomicAdd(&counts[threadIdx.x], lc[threadIdx.x]);
}

__global__ void k_scan(const int* __restrict__ counts, int* __restrict__ offsets) {
  if (threadIdx.x == 0) {
    int s = 0;
    for (int e = 0; e < NE; ++e) { offsets[e] = s; s += counts[e]; }
    offsets[NE] = s;
  }
}

__global__ void k_scatter(const int* __restrict__ idxs, const int* __restrict__ offsets,
                          int* __restrict__ cursor, int* __restrict__ perm) {
  int t = blockIdx.x * 256 + threadIdx.x;
  int e = idxs[t];
  int p = atomicAdd(&cursor[e], 1);
  perm[offsets[e] + p] = t;
}

// ---- W [E][k][n] (bf16 or fp32) -> Wt [E][n][k] bf16
__global__ void k_transpose(const void* __restrict__ Wsrc, short* __restrict__ Wt,
                            const int* __restrict__ flagp) {
  __shared__ unsigned short tile[64][66];  // stride 66 shorts: conflict-free column reads
  int b = blockIdx.x;
  int e  = b >> 8;
  int kt = (b >> 4) & 15;
  int nt = b & 15;
  int fp32 = *flagp;
  size_t ibase = (size_t)e * DIN * DOUT + (size_t)(kt * 64) * DOUT + nt * 64;
  #pragma unroll
  for (int i = 0; i < 16; ++i) {
    int fl = i * 256 + threadIdx.x;
    int k = fl >> 6, n = fl & 63;
    unsigned short uv;
    if (fp32) uv = (unsigned short)f2b(((const float*)Wsrc)[ibase + (size_t)k * DOUT + n]);
    else      uv = ((const unsigned short*)Wsrc)[ibase + (size_t)k * DOUT + n];
    tile[k][n] = uv;
  }
  __syncthreads();
  size_t obase = (size_t)e * DOUT * DIN + (size_t)(nt * 64) * DIN + kt * 64;
  #pragma unroll
  for (int i = 0; i < 16; ++i) {
    int fl = i * 256 + threadIdx.x;
    int n = fl >> 6, k = fl & 63;
    ((unsigned short*)Wt)[obase + (size_t)n * DIN + k] = tile[k][n];
  }
}

// ---- gather-GEMM: block = (expert e, n-tile nt, m-tile mt); early-exit if empty.
__launch_bounds__(256, 2)
__global__ void k_gemm(const void* __restrict__ xv,
                       const void* __restrict__ bv,
                       const short* __restrict__ Wt,
                       const int* __restrict__ counts,
                       const int* __restrict__ offsets,
                       const int* __restrict__ perm,
                       const int* __restrict__ flagp,
                       void* __restrict__ outv) {
  int b = blockIdx.x;
  int e  = b >> 10;          // 8 nt * 128 mt per expert
  int nt = (b >> 7) & 7;
  int mt = b & 127;
  int cnt = counts[e];
  int m0 = mt * BM;
  if (m0 >= cnt) return;
  int off = offsets[e];
  int fp32 = *flagp;

  int tid  = threadIdx.x;
  int lane = tid & 63;
  int wave = tid >> 6;

  __shared__ int   tokS[BM];
  __shared__ short lA[BM * BK];   // 8 KB, dense [m][k]
  __shared__ short lB[BN * BK];   // 8 KB, dense [n][k]

  if (tid < BM) {
    int m = m0 + tid;
    tokS[tid] = perm[off + (m < cnt ? m : (cnt - 1))];
  }
  __syncthreads();

  const short* WtE = Wt + (size_t)e * DOUT * DIN;
  const short* xs  = (const short*)xv;
  const float* xf  = (const float*)xv;

  // 512 16B-chunks per tile, 2 per thread. chunk fl: row = fl>>2, kc = fl&3.
  const short* bGlb[2];
  const short* aGlbB[2];
  const float* aGlbF[2];
  char* aLdsW[2];  // wave-uniform dst (glds adds lane*16)
  char* bLdsW[2];
  char* aLdsT[2];  // per-thread dst (manual fp32 convert path)
  #pragma unroll
  for (int s = 0; s < 2; ++s) {
    int fl = tid + s * 256;
    int r  = fl >> 2;
    int kc = fl & 3;
    bGlb[s]  = WtE + (size_t)(nt * BN + r) * DIN + kc * 8;
    aGlbB[s] = xs + (size_t)tokS[r] * DIN + kc * 8;
    aGlbF[s] = xf + (size_t)tokS[r] * DIN + kc * 8;
    int woff = (s * 256 + wave * 64) * 16;
    aLdsW[s] = (char*)lA + woff;
    bLdsW[s] = (char*)lB + woff;
    aLdsT[s] = (char*)lA + fl * 16;
  }

  int wm = wave & 1, wn = wave >> 1;
  int lrow = lane & 15, q = lane >> 4;
  int aOff[4], bOff[4];  // in shorts
  #pragma unroll
  for (int i = 0; i < 4; ++i) {
    aOff[i] = (wm * 64 + i * 16 + lrow) * BK + q * 8;
    bOff[i] = (wn * 64 + i * 16 + lrow) * BK + q * 8;
  }

  floatx4 acc[4][4];
  #pragma unroll
  for (int i = 0; i < 4; ++i)
    #pragma unroll
    for (int j = 0; j < 4; ++j)
      acc[i][j] = (floatx4){0.f, 0.f, 0.f, 0.f};

  for (int k0 = 0; k0 < DIN; k0 += BK) {
    __syncthreads();
    #pragma unroll
    for (int s = 0; s < 2; ++s)
      glds16(bGlb[s] + k0, bLdsW[s]);
    if (!fp32) {
      #pragma unroll
      for (int s = 0; s < 2; ++s)
        glds16(aGlbB[s] + k0, aLdsW[s]);
    } else {
      #pragma unroll
      for (int s = 0; s < 2; ++s) {
        const float* ap = aGlbF[s] + k0;
        floatx4 v0 = *(const floatx4*)ap;
        floatx4 v1 = *(const floatx4*)(ap + 4);
        short8 hv;
        hv[0]=f2b(v0[0]); hv[1]=f2b(v0[1]); hv[2]=f2b(v0[2]); hv[3]=f2b(v0[3]);
        hv[4]=f2b(v1[0]); hv[5]=f2b(v1[1]); hv[6]=f2b(v1[2]); hv[7]=f2b(v1[3]);
        *(short8*)aLdsT[s] = hv;
      }
    }
    __syncthreads();
    short8 af[4], bfr[4];
    #pragma unroll
    for (int i = 0; i < 4; ++i) af[i]  = *(const short8*)(lA + aOff[i]);
    #pragma unroll
    for (int j = 0; j < 4; ++j) bfr[j] = *(const short8*)(lB + bOff[j]);
    #pragma unroll
    for (int i = 0; i < 4; ++i)
      #pragma unroll
      for (int j = 0; j < 4; ++j)
        acc[i][j] = __builtin_amdgcn_mfma_f32_16x16x32_bf16(af[i], bfr[j], acc[i][j], 0, 0, 0);
  }

  // epilogue: bias + relu + masked scatter store (C/D: col=lane&15, row=q*4+reg)
  float bias[4];
  #pragma unroll
  for (int j = 0; j < 4; ++j) {
    int n = nt * BN + wn * 64 + j * 16 + lrow;
    bias[j] = fp32 ? ((const float*)bv)[e * DOUT + n]
                   : b2f(((const unsigned short*)bv)[e * DOUT + n]);
  }
  #pragma unroll
  for (int i = 0; i < 4; ++i) {
    #pragma unroll
    for (int r = 0; r < 4; ++r) {
      int lm = wm * 64 + i * 16 + q * 4 + r;
      if (m0 + lm < cnt) {
        size_t rowb = (size_t)tokS[lm] * DOUT + nt * BN + wn * 64 + lrow;
        #pragma unroll
        for (int j = 0; j < 4; ++j) {
          float v = acc[i][j][r] + bias[j];
          v = v > 0.f ? v : 0.f;
          if (fp32) ((float*)outv)[rowb + j * 16] = v;
          else      ((short*)outv)[rowb + j * 16] = f2b(v);
        }
      }
    }
  }
}

// ---- correct-but-slow fallback if ws is too small (no workspace needed)
__global__ void k_fallback(const void* __restrict__ xv, const int* __restrict__ idxs,
                           const void* __restrict__ Wv, const void* __restrict__ bv,
                           void* __restrict__ outv) {
  __shared__ float xrow[DIN];
  __shared__ int sflag;
  int t = blockIdx.x;
  int e = idxs[t];
  if (threadIdx.x == 0) {
    const unsigned short* u = (const unsigned short*)xv;
    int f = 0;
    for (int i = 0; i < 256; ++i) { int ex = (u[i] >> 7) & 0xFF; if (ex >= 0xC0) f = 1; }
    sflag = f;
  }
  __syncthreads();
  int fp32 = sflag;
  for (int i = threadIdx.x; i < DIN; i += 256)
    xrow[i] = fp32 ? ((const float*)xv)[(size_t)t * DIN + i]
                   : b2f(((const unsigned short*)xv)[(size_t)t * DIN + i]);
  __syncthreads();
  float a[4] = {0.f, 0.f, 0.f, 0.f};
  for (int k = 0; k < DIN; ++k) {
    float xk = xrow[k];
    size_t wb = (size_t)e * DIN * DOUT + (size_t)k * DOUT + threadIdx.x;
    #pragma unroll
    for (int j = 0; j < 4; ++j) {
      float w = fp32 ? ((const float*)Wv)[wb + j * 256]
                     : b2f(((const unsigned short*)Wv)[wb + j * 256]);
      a[j] += xk * w;
    }
  }
  #pragma unroll
  for (int j = 0; j < 4; ++j) {
    int n = threadIdx.x + j * 256;
    float bias = fp32 ? ((const float*)bv)[e * DOUT + n]
                      : b2f(((const unsigned short*)bv)[e * DOUT + n]);
    float v = a[j] + bias;
    v = v > 0.f ? v : 0.f;
    size_t o = (size_t)t * DOUT + n;
    if (fp32) ((float*)outv)[o] = v;
    else      ((short*)outv)[o] = f2b(v);
  }
}

extern "C" void kernel_launch(void* const* d_in, const int* in_sizes, int n_in,
                              void* d_out, int out_size, void* d_ws, size_t ws_size,
                              hipStream_t stream) {
  const void* x    = d_in[0];
  const int*  idxs = (const int*)d_in[1];
  const void* W    = d_in[2];
  const void* bias = d_in[3];

  // ws layout: flag@0, counts@256, offsets@512, cursor@768, perm@4096 (64KB),
  // Wt@69632 (16MB bf16)
  size_t need = 69632 + (size_t)NE * DIN * DOUT * 2;
  if (ws_size < need) {
    k_fallback<<<T_TOK, 256, 0, stream>>>(x, idxs, W, bias, d_out);
    return;
  }
  int* flag    = (int*)d_ws;
  int* counts  = (int*)((char*)d_ws + 256);
  int* offsets = (int*)((char*)d_ws + 512);
  int* cursor  = (int*)((char*)d_ws + 768);
  int* perm    = (int*)((char*)d_ws + 4096);
  short* Wt    = (short*)((char*)d_ws + 69632);

  k_detect<<<1, 64, 0, stream>>>((const unsigned short*)x, flag);
  k_zero<<<1, 64, 0, stream>>>(counts, cursor);
  k_hist<<<T_TOK / 256, 256, 0, stream>>>(idxs, counts);
  k_scan<<<1, 64, 0, stream>>>(counts, offsets);
  k_scatter<<<T_TOK / 256, 256, 0, stream>>>(idxs, offsets, cursor, perm);
  k_transpose<<<NE * 16 * 16, 256, 0, stream>>>(W, Wt, flag);
  k_gemm<<<NE * 8 * 128, 256, 0, stream>>>(x, bias, Wt, counts, offsets, perm, flag, d_out);
}

// Round 2
// 291.226 us; speedup vs baseline: 1.1461x; 1.1461x over previous
//
#include <hip/hip_runtime.h>
#include <hip/hip_bf16.h>
#include <stdint.h>

// MoE grouped linear: y[t] = relu(x[t] @ W[idxs[t]] + b[idxs[t]])
// T=16384, D_IN=D_OUT=1024, E=8.
// R2: materialize permuted+padded A (bf16) so the GEMM K-loop is pure m97
// structure (sequential A/B staging via global_load_lds w=16); parallel
// dtype-detect; compact tile table (grid 1088, not 8192).

#define T_TOK 16384
#define DIN   1024
#define DOUT  1024
#define NE    8
#define BM    128
#define BN    128
#define BK    32
#define MAX_TILES 136            // <= T/128 + E
#define MP_MAX (T_TOK + NE * BM) // 17408 padded rows max

typedef __attribute__((ext_vector_type(8))) short short8;
typedef __attribute__((ext_vector_type(4))) float floatx4;
typedef __attribute__((ext_vector_type(4))) int int4v;

__device__ __forceinline__ short f2b(float f) {
  return __builtin_bit_cast(short, __float2bfloat16(f));
}
__device__ __forceinline__ float b2f(unsigned short u) {
  unsigned v = ((unsigned)u) << 16;
  return __builtin_bit_cast(float, v);
}
__device__ __forceinline__ void glds16(const void* g, void* l) {
  __builtin_amdgcn_global_load_lds(
      (__attribute__((address_space(1))) void*)g,
      (__attribute__((address_space(3))) void*)l, 16, 0, 0);
}

// ws layout (bytes)
#define FLAG_OFF    0
#define NTILES_OFF  64
#define COUNTS_OFF  128
#define OFFSETS_OFF 256   // 9 ints
#define CURSOR_OFF  384
#define PADOFF_OFF  512   // 9 ints
#define TABLE_OFF   1024  // MAX_TILES * int4
#define PERM_OFF    4096
#define TPAD_OFF    69632
#define WT_OFF      139264
#define APERM_OFF   16916480
#define WS_NEED     (16916480UL + (size_t)MP_MAX * DIN * 2)

// ---- prep: zero counters + wave-parallel dtype detect.
// bf16 N(0,1) data never has exponent >= 0xC0; fp32 reinterpreted as ushorts
// has uniform-random exponents in low halves (P[miss in 256] ~ 1e-32).
__global__ void k_prep(const unsigned short* __restrict__ x, int* __restrict__ flag,
                       int* __restrict__ counts, int* __restrict__ cursor) {
  int tid = threadIdx.x;
  if (tid < NE) { counts[tid] = 0; cursor[tid] = 0; }
  int f = 0;
  #pragma unroll
  for (int i = 0; i < 4; ++i) {
    int ex = (x[tid * 4 + i] >> 7) & 0xFF;
    if (ex >= 0xC0) f = 1;
  }
  unsigned long long any = __ballot(f);
  if (tid == 0) *flag = any ? 1 : 0;
}

__global__ void k_hist(const int* __restrict__ idxs, int* __restrict__ counts) {
  __shared__ int lc[NE];
  if (threadIdx.x < NE) lc[threadIdx.x] = 0;
  __syncthreads();
  int t = blockIdx.x * 256 + threadIdx.x;
  atomicAdd(&lc[idxs[t]], 1);
  __syncthreads();
  if (threadIdx.x < NE) atomicAdd(&counts[threadIdx.x], lc[threadIdx.x]);
}

// serial scan + padded offsets + compact tile table
__global__ void k_scan(const int* __restrict__ counts, int* __restrict__ offsets,
                       int* __restrict__ padoff, int* __restrict__ ntiles,
                       int4v* __restrict__ table) {
  if (threadIdx.x == 0) {
    int s = 0, p = 0, t = 0;
    for (int e = 0; e < NE; ++e) {
      offsets[e] = s;
      padoff[e] = p;
      int c = counts[e];
      int nmt = (c + BM - 1) / BM;
      for (int m = 0; m < nmt; ++m) {
        table[t] = (int4v){e, p + m * BM, 0, 0};
        ++t;
      }
      s += c;
      p += nmt * BM;
    }
    offsets[NE] = s;
    padoff[NE] = p;
    *ntiles = t;
  }
}

__global__ void k_scatter(const int* __restrict__ idxs, const int* __restrict__ offsets,
                          int* __restrict__ cursor, int* __restrict__ perm) {
  int t = blockIdx.x * 256 + threadIdx.x;
  int e = idxs[t];
  int p = atomicAdd(&cursor[e], 1);
  perm[offsets[e] + p] = t;
}

// ---- fused staging: blocks [0,2048): W [E][k][n] -> Wt [E][n][k] bf16;
//      blocks [2048,..): gather x rows (permuted, padded, bf16) -> Aperm + tpad
#define TRANS_BLOCKS (NE * 16 * 16)
#define GATHER_BLOCKS (MP_MAX / 4)
__global__ void k_stage(const void* __restrict__ Wsrc, short* __restrict__ Wt,
                        const void* __restrict__ xv, short* __restrict__ Aperm,
                        int* __restrict__ tpad,
                        const int* __restrict__ counts, const int* __restrict__ offsets,
                        const int* __restrict__ padoff, const int* __restrict__ perm,
                        const int* __restrict__ flagp) {
  int tid = threadIdx.x;
  if (blockIdx.x < TRANS_BLOCKS) {
    __shared__ unsigned short tile[64][66];
    int b = blockIdx.x;
    int e = b >> 8;
    int kt = (b >> 4) & 15;
    int nt = b & 15;
    int fp32 = *flagp;
    size_t ibase = (size_t)e * DIN * DOUT + (size_t)(kt * 64) * DOUT + nt * 64;
    #pragma unroll
    for (int i = 0; i < 16; ++i) {
      int fl = i * 256 + tid;
      int k = fl >> 6, n = fl & 63;
      unsigned short uv;
      if (fp32) uv = (unsigned short)f2b(((const float*)Wsrc)[ibase + (size_t)k * DOUT + n]);
      else      uv = ((const unsigned short*)Wsrc)[ibase + (size_t)k * DOUT + n];
      tile[k][n] = uv;
    }
    __syncthreads();
    size_t obase = (size_t)e * DOUT * DIN + (size_t)(nt * 64) * DIN + kt * 64;
    #pragma unroll
    for (int i = 0; i < 16; ++i) {
      int fl = i * 256 + tid;
      int n = fl >> 6, k = fl & 63;
      ((unsigned short*)Wt)[obase + (size_t)n * DIN + k] = tile[k][n];
    }
    return;
  }
  // gather: 4 rows per block, 1 row per wave
  __shared__ int lpad[NE + 1], loff[NE], lcnt[NE];
  __shared__ int lflag;
  if (tid < NE + 1) lpad[tid] = padoff[tid];
  if (tid < NE) { loff[tid] = offsets[tid]; lcnt[tid] = counts[tid]; }
  if (tid == 0) lflag = *flagp;
  __syncthreads();
  int idx = blockIdx.x - TRANS_BLOCKS;
  int rb = idx * 4 + (tid >> 6);
  int lane = tid & 63;
  if (rb >= lpad[NE]) return;
  int e = 0;
  #pragma unroll
  for (int i = 0; i < NE - 1; ++i)
    if (rb >= lpad[i + 1]) e = i + 1;
  int local = rb - lpad[e];
  int tok = -1;
  if (local < lcnt[e]) tok = perm[loff[e] + local];
  if (lane == 0) tpad[rb] = tok;
  short8 v0 = {0, 0, 0, 0, 0, 0, 0, 0}, v1 = v0;
  if (tok >= 0) {
    if (lflag) {
      const float* xf = (const float*)xv + (size_t)tok * DIN + lane * 16;
      floatx4 a = *(const floatx4*)xf;
      floatx4 b = *(const floatx4*)(xf + 4);
      floatx4 c = *(const floatx4*)(xf + 8);
      floatx4 d = *(const floatx4*)(xf + 12);
      v0[0]=f2b(a[0]); v0[1]=f2b(a[1]); v0[2]=f2b(a[2]); v0[3]=f2b(a[3]);
      v0[4]=f2b(b[0]); v0[5]=f2b(b[1]); v0[6]=f2b(b[2]); v0[7]=f2b(b[3]);
      v1[0]=f2b(c[0]); v1[1]=f2b(c[1]); v1[2]=f2b(c[2]); v1[3]=f2b(c[3]);
      v1[4]=f2b(d[0]); v1[5]=f2b(d[1]); v1[6]=f2b(d[2]); v1[7]=f2b(d[3]);
    } else {
      const short* xs = (const short*)xv + (size_t)tok * DIN + lane * 16;
      v0 = *(const short8*)xs;
      v1 = *(const short8*)(xs + 8);
    }
  }
  short* dst = Aperm + (size_t)rb * DIN + lane * 16;
  *(short8*)dst = v0;
  *(short8*)(dst + 8) = v1;
}

// ---- m97-structure GEMM over permuted A; epilogue bias+relu+scatter by token id
__launch_bounds__(256)
__global__ void k_gemm(const short* __restrict__ Aperm, const void* __restrict__ bv,
                       const short* __restrict__ Wt, const int* __restrict__ tpad,
                       const int* __restrict__ ntilesp, const int4v* __restrict__ table,
                       const int* __restrict__ flagp, void* __restrict__ outv) {
  int b = blockIdx.x;
  int t = b >> 3;       // consecutive b: same A-tile, different nt (nt = b&7 keeps
  int nt = b & 7;       // B-tile reuse on the same XCD under %8 round-robin)
  if (t >= *ntilesp) return;
  int4v te = table[t];
  int e = te.x, arow0 = te.y;
  int fp32 = *flagp;

  int tid = threadIdx.x;
  int lane = tid & 63;
  int wave = tid >> 6;

  __shared__ int tokS[BM];
  __shared__ short lA[BM * BK];  // 8 KB dense [m][k]
  __shared__ short lB[BN * BK];  // 8 KB dense [n][k]

  if (tid < BM) tokS[tid] = tpad[arow0 + tid];

  const short* WtE = Wt + (size_t)e * DOUT * DIN;

  // 512 16B chunks per tile, 2 per thread; chunk fl: row = fl>>2, kc = fl&3
  const short* aGlb[2];
  const short* bGlb[2];
  char* aLdsW[2];
  char* bLdsW[2];
  #pragma unroll
  for (int s = 0; s < 2; ++s) {
    int fl = tid + s * 256;
    int r = fl >> 2;
    int kc = fl & 3;
    aGlb[s] = Aperm + (size_t)(arow0 + r) * DIN + kc * 8;
    bGlb[s] = WtE + (size_t)(nt * BN + r) * DIN + kc * 8;
    int woff = (s * 256 + wave * 64) * 16;
    aLdsW[s] = (char*)lA + woff;
    bLdsW[s] = (char*)lB + woff;
  }

  int wm = wave & 1, wn = wave >> 1;
  int lrow = lane & 15, q = lane >> 4;
  int aOff[4], bOff[4];  // shorts
  #pragma unroll
  for (int i = 0; i < 4; ++i) {
    aOff[i] = (wm * 64 + i * 16 + lrow) * BK + q * 8;
    bOff[i] = (wn * 64 + i * 16 + lrow) * BK + q * 8;
  }

  floatx4 acc[4][4];
  #pragma unroll
  for (int i = 0; i < 4; ++i)
    #pragma unroll
    for (int j = 0; j < 4; ++j)
      acc[i][j] = (floatx4){0.f, 0.f, 0.f, 0.f};

  for (int k0 = 0; k0 < DIN; k0 += BK) {
    __syncthreads();
    #pragma unroll
    for (int s = 0; s < 2; ++s) glds16(bGlb[s] + k0, bLdsW[s]);
    #pragma unroll
    for (int s = 0; s < 2; ++s) glds16(aGlb[s] + k0, aLdsW[s]);
    __syncthreads();
    short8 af[4], bfr[4];
    #pragma unroll
    for (int i = 0; i < 4; ++i) af[i] = *(const short8*)(lA + aOff[i]);
    #pragma unroll
    for (int j = 0; j < 4; ++j) bfr[j] = *(const short8*)(lB + bOff[j]);
    #pragma unroll
    for (int i = 0; i < 4; ++i)
      #pragma unroll
      for (int j = 0; j < 4; ++j)
        acc[i][j] = __builtin_amdgcn_mfma_f32_16x16x32_bf16(af[i], bfr[j], acc[i][j], 0, 0, 0);
  }

  // epilogue (C/D: col=lane&15, row=q*4+reg)
  float bias[4];
  #pragma unroll
  for (int j = 0; j < 4; ++j) {
    int n = nt * BN + wn * 64 + j * 16 + lrow;
    bias[j] = fp32 ? ((const float*)bv)[e * DOUT + n]
                   : b2f(((const unsigned short*)bv)[e * DOUT + n]);
  }
  #pragma unroll
  for (int i = 0; i < 4; ++i) {
    #pragma unroll
    for (int r = 0; r < 4; ++r) {
      int lm = wm * 64 + i * 16 + q * 4 + r;
      int tok = tokS[lm];
      if (tok >= 0) {
        size_t rowb = (size_t)tok * DOUT + nt * BN + wn * 64 + lrow;
        #pragma unroll
        for (int j = 0; j < 4; ++j) {
          float v = acc[i][j][r] + bias[j];
          v = v > 0.f ? v : 0.f;
          if (fp32) ((float*)outv)[rowb + j * 16] = v;
          else      ((short*)outv)[rowb + j * 16] = f2b(v);
        }
      }
    }
  }
}

// ---- correct-but-slow fallback if ws too small
__global__ void k_fallback(const void* __restrict__ xv, const int* __restrict__ idxs,
                           const void* __restrict__ Wv, const void* __restrict__ bv,
                           void* __restrict__ outv) {
  __shared__ float xrow[DIN];
  __shared__ int sflag;
  int t = blockIdx.x;
  int e = idxs[t];
  if (threadIdx.x == 0) {
    const unsigned short* u = (const unsigned short*)xv;
    int f = 0;
    for (int i = 0; i < 256; ++i) { int ex = (u[i] >> 7) & 0xFF; if (ex >= 0xC0) f = 1; }
    sflag = f;
  }
  __syncthreads();
  int fp32 = sflag;
  for (int i = threadIdx.x; i < DIN; i += 256)
    xrow[i] = fp32 ? ((const float*)xv)[(size_t)t * DIN + i]
                   : b2f(((const unsigned short*)xv)[(size_t)t * DIN + i]);
  __syncthreads();
  float a[4] = {0.f, 0.f, 0.f, 0.f};
  for (int k = 0; k < DIN; ++k) {
    float xk = xrow[k];
    size_t wb = (size_t)e * DIN * DOUT + (size_t)k * DOUT + threadIdx.x;
    #pragma unroll
    for (int j = 0; j < 4; ++j) {
      float w = fp32 ? ((const float*)Wv)[wb + j * 256]
                     : b2f(((const unsigned short*)Wv)[wb + j * 256]);
      a[j] += xk * w;
    }
  }
  #pragma unroll
  for (int j = 0; j < 4; ++j) {
    int n = threadIdx.x + j * 256;
    float bias = fp32 ? ((const float*)bv)[e * DOUT + n]
                      : b2f(((const unsigned short*)bv)[e * DOUT + n]);
    float v = a[j] + bias;
    v = v > 0.f ? v : 0.f;
    size_t o = (size_t)t * DOUT + n;
    if (fp32) ((float*)outv)[o] = v;
    else      ((short*)outv)[o] = f2b(v);
  }
}

extern "C" void kernel_launch(void* const* d_in, const int* in_sizes, int n_in,
                              void* d_out, int out_size, void* d_ws, size_t ws_size,
                              hipStream_t stream) {
  const void* x    = d_in[0];
  const int*  idxs = (const int*)d_in[1];
  const void* W    = d_in[2];
  const void* bias = d_in[3];

  if (ws_size < WS_NEED) {
    k_fallback<<<T_TOK, 256, 0, stream>>>(x, idxs, W, bias, d_out);
    return;
  }
  char* ws = (char*)d_ws;
  int* flag    = (int*)(ws + FLAG_OFF);
  int* ntiles  = (int*)(ws + NTILES_OFF);
  int* counts  = (int*)(ws + COUNTS_OFF);
  int* offsets = (int*)(ws + OFFSETS_OFF);
  int* cursor  = (int*)(ws + CURSOR_OFF);
  int* padoff  = (int*)(ws + PADOFF_OFF);
  int4v* table = (int4v*)(ws + TABLE_OFF);
  int* perm    = (int*)(ws + PERM_OFF);
  int* tpad    = (int*)(ws + TPAD_OFF);
  short* Wt    = (short*)(ws + WT_OFF);
  short* Aperm = (short*)(ws + APERM_OFF);

  k_prep<<<1, 64, 0, stream>>>((const unsigned short*)x, flag, counts, cursor);
  k_hist<<<T_TOK / 256, 256, 0, stream>>>(idxs, counts);
  k_scan<<<1, 64, 0, stream>>>(counts, offsets, padoff, ntiles, table);
  k_scatter<<<T_TOK / 256, 256, 0, stream>>>(idxs, offsets, cursor, perm);
  k_stage<<<TRANS_BLOCKS + GATHER_BLOCKS, 256, 0, stream>>>(
      W, Wt, x, Aperm, tpad, counts, offsets, padoff, perm, flag);
  k_gemm<<<MAX_TILES * 8, 256, 0, stream>>>(Aperm, bias, Wt, tpad, ntiles, table, flag, d_out);
}

// Round 3
// 287.700 us; speedup vs baseline: 1.1601x; 1.0123x over previous
//
#include <hip/hip_runtime.h>
#include <hip/hip_bf16.h>
#include <stdint.h>

// MoE grouped linear: y[t] = relu(x[t] @ W[idxs[t]] + b[idxs[t]])
// T=16384, D_IN=D_OUT=1024, E=8.
// R3: 4 launches (prep -> scatter -> stage -> gemm). GEMM: BK=64 (2x 8KB
// sub-buffers, proven BK=32 inner layout), operand-swapped MFMA so epilogue
// stores are 8-B vectors, XCD-aware tile swizzle for L2 reuse.

#define T_TOK 16384
#define DIN   1024
#define DOUT  1024
#define NE    8
#define BM    128
#define BN    128
#define BK    32
#define TPX   17                  // tiles per XCD slot (8*17 = 136 = MAX_TILES)
#define MAX_TILES 136
#define MP_MAX (T_TOK + NE * BM)  // 17408 padded rows max

typedef __attribute__((ext_vector_type(8))) short short8;
typedef __attribute__((ext_vector_type(4))) short short4v;
typedef __attribute__((ext_vector_type(4))) float floatx4;
typedef __attribute__((ext_vector_type(4))) int int4v;

__device__ __forceinline__ short f2b(float f) {
  return __builtin_bit_cast(short, __float2bfloat16(f));
}
__device__ __forceinline__ float b2f(unsigned short u) {
  unsigned v = ((unsigned)u) << 16;
  return __builtin_bit_cast(float, v);
}
__device__ __forceinline__ void glds16(const void* g, void* l) {
  __builtin_amdgcn_global_load_lds(
      (__attribute__((address_space(1))) void*)g,
      (__attribute__((address_space(3))) void*)l, 16, 0, 0);
}

// ws layout (bytes)
#define FLAG_OFF    0
#define NTILES_OFF  64
#define COUNTS_OFF  128
#define CURSOR_OFF  384
#define PADOFF_OFF  512   // 9 ints
#define TABLE_OFF   1024  // MAX_TILES * int4
#define TPAD_OFF    4096  // MP_MAX ints (token id per padded row, -1 = pad)
#define WT_OFF      73728 // 16 MB bf16 [E][n][k]
#define APERM_OFF   16850944
#define WS_NEED     (16850944UL + (size_t)MP_MAX * DIN * 2)

// ---- fused prep: dtype detect + histogram + scan + tile table + tpad=-1 init.
// bf16 N(0,1) data never has exponent >= 0xC0; fp32 reinterpreted as ushorts
// has uniform-random exponents in low halves.
__global__ void k_prep(const unsigned short* __restrict__ x, const int* __restrict__ idxs,
                       int* __restrict__ flag, int* __restrict__ cursor,
                       int* __restrict__ countsG, int* __restrict__ padoffG,
                       int* __restrict__ ntiles, int4v* __restrict__ table,
                       int* __restrict__ tpad) {
  __shared__ int hist[16][9];  // 16 sub-hists, padded rows (bank spread)
  int tid = threadIdx.x;
  if (tid < 16 * 9) ((int*)hist)[tid] = 0;
  int f = 0;
  if (tid < 64) {
    #pragma unroll
    for (int i = 0; i < 4; ++i) {
      int ex = (x[tid * 4 + i] >> 7) & 0xFF;
      if (ex >= 0xC0) f = 1;
    }
  }
  unsigned long long any = __ballot(f);
  if (tid == 0) *flag = any ? 1 : 0;
  if (tid < NE) cursor[tid] = 0;
  __syncthreads();
  int sub = tid >> 6;
  const int4v* iv = (const int4v*)idxs;
  #pragma unroll
  for (int it = 0; it < 4; ++it) {
    int4v v = iv[it * 1024 + tid];
    atomicAdd(&hist[sub][v.x], 1);
    atomicAdd(&hist[sub][v.y], 1);
    atomicAdd(&hist[sub][v.z], 1);
    atomicAdd(&hist[sub][v.w], 1);
  }
  __syncthreads();
  if (tid == 0) {
    int p = 0, tc = 0;
    for (int e = 0; e < NE; ++e) {
      int c = 0;
      for (int s = 0; s < 16; ++s) c += hist[s][e];
      countsG[e] = c;
      padoffG[e] = p;
      int nmt = (c + BM - 1) / BM;
      for (int m = 0; m < nmt; ++m) table[tc++] = (int4v){e, p + m * BM, 0, 0};
      p += nmt * BM;
    }
    padoffG[NE] = p;
    *ntiles = tc;
  }
  // tpad = -1 everywhere (scatter overwrites real tokens; rest stay pads)
  const int4v neg = (int4v){-1, -1, -1, -1};
  #pragma unroll
  for (int it = 0; it < 5; ++it) {
    int idx = it * 1024 + tid;
    if (idx < MP_MAX / 4) ((int4v*)tpad)[idx] = neg;
  }
}

// ---- scatter tokens directly into padded slots
__global__ void k_scatter(const int* __restrict__ idxs, const int* __restrict__ padoffG,
                          int* __restrict__ cursor, int* __restrict__ tpad) {
  int t = blockIdx.x * 256 + threadIdx.x;
  int e = idxs[t];
  int p = atomicAdd(&cursor[e], 1);
  tpad[padoffG[e] + p] = t;
}

// ---- fused staging: blocks [0,2048): W [E][k][n] -> Wt [E][n][k] bf16 (vectorized);
//      blocks [2048,..): gather x rows (permuted, padded, bf16) -> Aperm
#define TRANS_BLOCKS (NE * 16 * 16)
#define GATHER_BLOCKS (MP_MAX / 4)
__global__ void k_stage(const void* __restrict__ Wsrc, short* __restrict__ Wt,
                        const void* __restrict__ xv, short* __restrict__ Aperm,
                        const int* __restrict__ padoffG, const int* __restrict__ tpad,
                        const int* __restrict__ flagp) {
  int tid = threadIdx.x;
  int fp32 = *flagp;
  if (blockIdx.x < TRANS_BLOCKS) {
    __shared__ unsigned short tile[64][66];
    int b = blockIdx.x;
    int e = b >> 8;
    int kt = (b >> 4) & 15;
    int nt = b & 15;
    size_t ibase = (size_t)e * DIN * DOUT + (size_t)(kt * 64) * DOUT + nt * 64;
    #pragma unroll
    for (int it = 0; it < 2; ++it) {
      int c = it * 256 + tid;
      int k = c >> 3, n8 = (c & 7) * 8;
      short8 v;
      if (fp32) {
        const float* p = (const float*)Wsrc + ibase + (size_t)k * DOUT + n8;
        floatx4 a = *(const floatx4*)p;
        floatx4 b4 = *(const floatx4*)(p + 4);
        v[0]=f2b(a[0]); v[1]=f2b(a[1]); v[2]=f2b(a[2]); v[3]=f2b(a[3]);
        v[4]=f2b(b4[0]); v[5]=f2b(b4[1]); v[6]=f2b(b4[2]); v[7]=f2b(b4[3]);
      } else {
        v = *(const short8*)((const short*)Wsrc + ibase + (size_t)k * DOUT + n8);
      }
      #pragma unroll
      for (int jj = 0; jj < 8; ++jj) tile[k][n8 + jj] = (unsigned short)v[jj];
    }
    __syncthreads();
    size_t obase = (size_t)e * DOUT * DIN + (size_t)(nt * 64) * DIN + kt * 64;
    #pragma unroll
    for (int it = 0; it < 2; ++it) {
      int c = it * 256 + tid;
      int n = c >> 3, k8 = (c & 7) * 8;
      short8 o;
      #pragma unroll
      for (int jj = 0; jj < 8; ++jj) o[jj] = (short)tile[k8 + jj][n];
      *(short8*)(Wt + obase + (size_t)n * DIN + k8) = o;
    }
    return;
  }
  // gather: 1 padded row per wave
  int mp = padoffG[NE];
  int rb = (blockIdx.x - TRANS_BLOCKS) * 4 + (tid >> 6);
  int lane = tid & 63;
  if (rb >= mp) return;
  int tok = tpad[rb];  // wave-uniform
  short8 v0 = {0, 0, 0, 0, 0, 0, 0, 0}, v1 = v0;
  if (tok >= 0) {
    if (fp32) {
      const float* xf = (const float*)xv + (size_t)tok * DIN + lane * 16;
      floatx4 a = *(const floatx4*)xf;
      floatx4 b = *(const floatx4*)(xf + 4);
      floatx4 c = *(const floatx4*)(xf + 8);
      floatx4 d = *(const floatx4*)(xf + 12);
      v0[0]=f2b(a[0]); v0[1]=f2b(a[1]); v0[2]=f2b(a[2]); v0[3]=f2b(a[3]);
      v0[4]=f2b(b[0]); v0[5]=f2b(b[1]); v0[6]=f2b(b[2]); v0[7]=f2b(b[3]);
      v1[0]=f2b(c[0]); v1[1]=f2b(c[1]); v1[2]=f2b(c[2]); v1[3]=f2b(c[3]);
      v1[4]=f2b(d[0]); v1[5]=f2b(d[1]); v1[6]=f2b(d[2]); v1[7]=f2b(d[3]);
    } else {
      const short* xs = (const short*)xv + (size_t)tok * DIN + lane * 16;
      v0 = *(const short8*)xs;
      v1 = *(const short8*)(xs + 8);
    }
  }
  short* dst = Aperm + (size_t)rb * DIN + lane * 16;
  *(short8*)dst = v0;
  *(short8*)(dst + 8) = v1;
}

// ---- GEMM: BK=64 via 2x 8KB sub-buffers; operand-swapped MFMA (reg r <-> n,
// contiguous) for vectorized scattered epilogue; XCD-aware tile swizzle.
__launch_bounds__(256)
__global__ void k_gemm(const short* __restrict__ Aperm, const void* __restrict__ bv,
                       const short* __restrict__ Wt, const int* __restrict__ tpad,
                       const int* __restrict__ ntilesp, const int4v* __restrict__ table,
                       const int* __restrict__ flagp, void* __restrict__ outv) {
  int bid = blockIdx.x;
  int xcd = bid & 7;
  int s = bid >> 3;
  int nt = s & 7;
  int ti = s >> 3;                 // [0, TPX)
  int t = xcd * TPX + ti;          // contiguous A-tile range per XCD
  if (t >= *ntilesp) return;
  int4v te = table[t];
  int e = te.x, arow0 = te.y;
  int fp32 = *flagp;

  int tid = threadIdx.x;
  int lane = tid & 63;
  int wave = tid >> 6;

  __shared__ short lA[2][BM * BK];  // 2 x 8 KB, dense [m][k] per sub-buffer
  __shared__ short lB[2][BN * BK];
  __shared__ int tokS[BM];

  const short* WtE = Wt + (size_t)e * DOUT * DIN + (size_t)(nt * BN) * DIN;
  const short* aBase = Aperm + (size_t)arow0 * DIN;

  // per sub-buffer: 512 16B chunks, 2 per thread; chunk fl: row = fl>>2, kc = fl&3
  const short* aG[2];
  const short* bG[2];
  char* aL[2][2];
  char* bL[2][2];
  #pragma unroll
  for (int s4 = 0; s4 < 2; ++s4) {
    int fl = tid + s4 * 256;
    int r = fl >> 2;
    int kc = fl & 3;
    aG[s4] = aBase + (size_t)r * DIN + kc * 8;
    bG[s4] = WtE + (size_t)r * DIN + kc * 8;
    int woff = (s4 * 256 + wave * 64) * 16;
    #pragma unroll
    for (int h = 0; h < 2; ++h) {
      aL[h][s4] = (char*)lA[h] + woff;
      bL[h][s4] = (char*)lB[h] + woff;
    }
  }

  int wm = wave & 1, wn = wave >> 1;
  int lrow = lane & 15, q = lane >> 4;
  int aOff[4], bOff[4];  // shorts, within a sub-buffer
  #pragma unroll
  for (int i = 0; i < 4; ++i) {
    aOff[i] = (wm * 64 + i * 16 + lrow) * BK + q * 8;
    bOff[i] = (wn * 64 + i * 16 + lrow) * BK + q * 8;
  }

  floatx4 acc[4][4];
  #pragma unroll
  for (int i = 0; i < 4; ++i)
    #pragma unroll
    for (int j = 0; j < 4; ++j)
      acc[i][j] = (floatx4){0.f, 0.f, 0.f, 0.f};

  for (int k0 = 0; k0 < DIN; k0 += 2 * BK) {
    __syncthreads();
    #pragma unroll
    for (int h = 0; h < 2; ++h)
      #pragma unroll
      for (int s4 = 0; s4 < 2; ++s4)
        glds16(bG[s4] + k0 + h * BK, bL[h][s4]);
    #pragma unroll
    for (int h = 0; h < 2; ++h)
      #pragma unroll
      for (int s4 = 0; s4 < 2; ++s4)
        glds16(aG[s4] + k0 + h * BK, aL[h][s4]);
    __syncthreads();
    #pragma unroll
    for (int h = 0; h < 2; ++h) {
      short8 af[4], bf[4];
      #pragma unroll
      for (int i = 0; i < 4; ++i) af[i] = *(const short8*)(lA[h] + aOff[i]);
      #pragma unroll
      for (int j = 0; j < 4; ++j) bf[j] = *(const short8*)(lB[h] + bOff[j]);
      // SWAPPED operands: D[p][c] = sum_k Wt[j*16+p][k] * A[i*16+c][k]
      // => token row m = i*16 + lrow, n = j*16 + q*4 + r (regs contiguous in n)
      #pragma unroll
      for (int i = 0; i < 4; ++i)
        #pragma unroll
        for (int j = 0; j < 4; ++j)
          acc[i][j] = __builtin_amdgcn_mfma_f32_16x16x32_bf16(bf[j], af[i], acc[i][j], 0, 0, 0);
    }
  }

  if (tid < BM) tokS[tid] = tpad[arow0 + tid];
  __syncthreads();

  // bias: 4 consecutive n per frag, n = nt*128 + wn*64 + j*16 + q*4 + r
  float bias[4][4];
  #pragma unroll
  for (int j = 0; j < 4; ++j) {
    int n = nt * BN + wn * 64 + j * 16 + q * 4;
    if (fp32) {
      floatx4 b4 = *(const floatx4*)((const float*)bv + e * DOUT + n);
      #pragma unroll
      for (int r = 0; r < 4; ++r) bias[j][r] = b4[r];
    } else {
      short4v b4 = *(const short4v*)((const short*)bv + e * DOUT + n);
      #pragma unroll
      for (int r = 0; r < 4; ++r) bias[j][r] = b2f((unsigned short)b4[r]);
    }
  }
  #pragma unroll
  for (int i = 0; i < 4; ++i) {
    int tok = tokS[wm * 64 + i * 16 + lrow];
    if (tok < 0) continue;
    size_t rowb = (size_t)tok * DOUT + nt * BN + wn * 64 + q * 4;
    #pragma unroll
    for (int j = 0; j < 4; ++j) {
      if (fp32) {
        floatx4 o;
        #pragma unroll
        for (int r = 0; r < 4; ++r) {
          float v = acc[i][j][r] + bias[j][r];
          o[r] = v > 0.f ? v : 0.f;
        }
        *(floatx4*)((float*)outv + rowb + j * 16) = o;
      } else {
        short4v o;
        #pragma unroll
        for (int r = 0; r < 4; ++r) {
          float v = acc[i][j][r] + bias[j][r];
          o[r] = f2b(v > 0.f ? v : 0.f);
        }
        *(short4v*)((short*)outv + rowb + j * 16) = o;
      }
    }
  }
}

// ---- correct-but-slow fallback if ws too small
__global__ void k_fallback(const void* __restrict__ xv, const int* __restrict__ idxs,
                           const void* __restrict__ Wv, const void* __restrict__ bv,
                           void* __restrict__ outv) {
  __shared__ float xrow[DIN];
  __shared__ int sflag;
  int t = blockIdx.x;
  int e = idxs[t];
  if (threadIdx.x == 0) {
    const unsigned short* u = (const unsigned short*)xv;
    int f = 0;
    for (int i = 0; i < 256; ++i) { int ex = (u[i] >> 7) & 0xFF; if (ex >= 0xC0) f = 1; }
    sflag = f;
  }
  __syncthreads();
  int fp32 = sflag;
  for (int i = threadIdx.x; i < DIN; i += 256)
    xrow[i] = fp32 ? ((const float*)xv)[(size_t)t * DIN + i]
                   : b2f(((const unsigned short*)xv)[(size_t)t * DIN + i]);
  __syncthreads();
  float a[4] = {0.f, 0.f, 0.f, 0.f};
  for (int k = 0; k < DIN; ++k) {
    float xk = xrow[k];
    size_t wb = (size_t)e * DIN * DOUT + (size_t)k * DOUT + threadIdx.x;
    #pragma unroll
    for (int j = 0; j < 4; ++j) {
      float w = fp32 ? ((const float*)Wv)[wb + j * 256]
                     : b2f(((const unsigned short*)Wv)[wb + j * 256]);
      a[j] += xk * w;
    }
  }
  #pragma unroll
  for (int j = 0; j < 4; ++j) {
    int n = threadIdx.x + j * 256;
    float bias = fp32 ? ((const float*)bv)[e * DOUT + n]
                      : b2f(((const unsigned short*)bv)[e * DOUT + n]);
    float v = a[j] + bias;
    v = v > 0.f ? v : 0.f;
    size_t o = (size_t)t * DOUT + n;
    if (fp32) ((float*)outv)[o] = v;
    else      ((short*)outv)[o] = f2b(v);
  }
}

extern "C" void kernel_launch(void* const* d_in, const int* in_sizes, int n_in,
                              void* d_out, int out_size, void* d_ws, size_t ws_size,
                              hipStream_t stream) {
  const void* x    = d_in[0];
  const int*  idxs = (const int*)d_in[1];
  const void* W    = d_in[2];
  const void* bias = d_in[3];

  if (ws_size < WS_NEED) {
    k_fallback<<<T_TOK, 256, 0, stream>>>(x, idxs, W, bias, d_out);
    return;
  }
  char* ws = (char*)d_ws;
  int* flag    = (int*)(ws + FLAG_OFF);
  int* ntiles  = (int*)(ws + NTILES_OFF);
  int* counts  = (int*)(ws + COUNTS_OFF);
  int* cursor  = (int*)(ws + CURSOR_OFF);
  int* padoff  = (int*)(ws + PADOFF_OFF);
  int4v* table = (int4v*)(ws + TABLE_OFF);
  int* tpad    = (int*)(ws + TPAD_OFF);
  short* Wt    = (short*)(ws + WT_OFF);
  short* Aperm = (short*)(ws + APERM_OFF);

  k_prep<<<1, 1024, 0, stream>>>((const unsigned short*)x, idxs, flag, cursor,
                                 counts, padoff, ntiles, table, tpad);
  k_scatter<<<T_TOK / 256, 256, 0, stream>>>(idxs, padoff, cursor, tpad);
  k_stage<<<TRANS_BLOCKS + GATHER_BLOCKS, 256, 0, stream>>>(
      W, Wt, x, Aperm, padoff, tpad, flag);
  k_gemm<<<8 * 8 * TPX, 256, 0, stream>>>(Aperm, bias, Wt, tpad, ntiles, table, flag, d_out);
}

// Round 4
// 285.743 us; speedup vs baseline: 1.1681x; 1.0068x over previous
//
#include <hip/hip_runtime.h>
#include <hip/hip_bf16.h>
#include <stdint.h>

// MoE grouped linear: y[t] = relu(x[t] @ W[idxs[t]] + b[idxs[t]])
// T=16384, D_IN=D_OUT=1024, E=8.
// R4: GEMM reverted to BK=32 (R2 inner loop, faster than BK=64), BN halved
// to 64 -> grid 2176 blocks (~8.5/CU) for latency hiding; launch_bounds(256,6);
// keeps XCD swizzle (R3: fetch 145->45MB) + operand-swapped vector epilogue.

#define T_TOK 16384
#define DIN   1024
#define DOUT  1024
#define NE    8
#define BM    128
#define BN    64
#define BK    32
#define TPX   17                  // A-tiles per XCD slot (8*17 = 136)
#define MAX_TILES 136
#define MP_MAX (T_TOK + NE * BM)  // 17408 padded rows max

typedef __attribute__((ext_vector_type(8))) short short8;
typedef __attribute__((ext_vector_type(4))) short short4v;
typedef __attribute__((ext_vector_type(4))) float floatx4;
typedef __attribute__((ext_vector_type(4))) int int4v;

__device__ __forceinline__ short f2b(float f) {
  return __builtin_bit_cast(short, __float2bfloat16(f));
}
__device__ __forceinline__ float b2f(unsigned short u) {
  unsigned v = ((unsigned)u) << 16;
  return __builtin_bit_cast(float, v);
}
__device__ __forceinline__ void glds16(const void* g, void* l) {
  __builtin_amdgcn_global_load_lds(
      (__attribute__((address_space(1))) void*)g,
      (__attribute__((address_space(3))) void*)l, 16, 0, 0);
}

// ws layout (bytes)
#define FLAG_OFF    0
#define NTILES_OFF  64
#define COUNTS_OFF  128
#define CURSOR_OFF  384
#define PADOFF_OFF  512   // 9 ints
#define TABLE_OFF   1024  // MAX_TILES * int4
#define TPAD_OFF    4096  // MP_MAX ints (token id per padded row, -1 = pad)
#define WT_OFF      73728 // 16 MB bf16 [E][n][k]
#define APERM_OFF   16850944
#define WS_NEED     (16850944UL + (size_t)MP_MAX * DIN * 2)

// ---- fused prep: dtype detect + histogram + scan + tile table + tpad=-1 init.
__global__ void k_prep(const unsigned short* __restrict__ x, const int* __restrict__ idxs,
                       int* __restrict__ flag, int* __restrict__ cursor,
                       int* __restrict__ countsG, int* __restrict__ padoffG,
                       int* __restrict__ ntiles, int4v* __restrict__ table,
                       int* __restrict__ tpad) {
  __shared__ int hist[16][9];
  int tid = threadIdx.x;
  if (tid < 16 * 9) ((int*)hist)[tid] = 0;
  int f = 0;
  if (tid < 64) {
    #pragma unroll
    for (int i = 0; i < 4; ++i) {
      int ex = (x[tid * 4 + i] >> 7) & 0xFF;
      if (ex >= 0xC0) f = 1;
    }
  }
  unsigned long long any = __ballot(f);
  if (tid == 0) *flag = any ? 1 : 0;
  if (tid < NE) cursor[tid] = 0;
  __syncthreads();
  int sub = tid >> 6;
  const int4v* iv = (const int4v*)idxs;
  #pragma unroll
  for (int it = 0; it < 4; ++it) {
    int4v v = iv[it * 1024 + tid];
    atomicAdd(&hist[sub][v.x], 1);
    atomicAdd(&hist[sub][v.y], 1);
    atomicAdd(&hist[sub][v.z], 1);
    atomicAdd(&hist[sub][v.w], 1);
  }
  __syncthreads();
  if (tid == 0) {
    int p = 0, tc = 0;
    for (int e = 0; e < NE; ++e) {
      int c = 0;
      for (int s = 0; s < 16; ++s) c += hist[s][e];
      countsG[e] = c;
      padoffG[e] = p;
      int nmt = (c + BM - 1) / BM;
      for (int m = 0; m < nmt; ++m) table[tc++] = (int4v){e, p + m * BM, 0, 0};
      p += nmt * BM;
    }
    padoffG[NE] = p;
    *ntiles = tc;
  }
  const int4v neg = (int4v){-1, -1, -1, -1};
  #pragma unroll
  for (int it = 0; it < 5; ++it) {
    int idx = it * 1024 + tid;
    if (idx < MP_MAX / 4) ((int4v*)tpad)[idx] = neg;
  }
}

// ---- scatter tokens directly into padded slots
__global__ void k_scatter(const int* __restrict__ idxs, const int* __restrict__ padoffG,
                          int* __restrict__ cursor, int* __restrict__ tpad) {
  int t = blockIdx.x * 256 + threadIdx.x;
  int e = idxs[t];
  int p = atomicAdd(&cursor[e], 1);
  tpad[padoffG[e] + p] = t;
}

// ---- fused staging: blocks [0,2048): W [E][k][n] -> Wt [E][n][k] bf16;
//      blocks [2048,..): gather x rows (permuted, padded, bf16) -> Aperm
#define TRANS_BLOCKS (NE * 16 * 16)
#define GATHER_BLOCKS (MP_MAX / 4)
__global__ void k_stage(const void* __restrict__ Wsrc, short* __restrict__ Wt,
                        const void* __restrict__ xv, short* __restrict__ Aperm,
                        const int* __restrict__ padoffG, const int* __restrict__ tpad,
                        const int* __restrict__ flagp) {
  int tid = threadIdx.x;
  int fp32 = *flagp;
  if (blockIdx.x < TRANS_BLOCKS) {
    __shared__ unsigned short tile[64][66];
    int b = blockIdx.x;
    int e = b >> 8;
    int kt = (b >> 4) & 15;
    int nt = b & 15;
    size_t ibase = (size_t)e * DIN * DOUT + (size_t)(kt * 64) * DOUT + nt * 64;
    #pragma unroll
    for (int it = 0; it < 2; ++it) {
      int c = it * 256 + tid;
      int k = c >> 3, n8 = (c & 7) * 8;
      short8 v;
      if (fp32) {
        const float* p = (const float*)Wsrc + ibase + (size_t)k * DOUT + n8;
        floatx4 a = *(const floatx4*)p;
        floatx4 b4 = *(const floatx4*)(p + 4);
        v[0]=f2b(a[0]); v[1]=f2b(a[1]); v[2]=f2b(a[2]); v[3]=f2b(a[3]);
        v[4]=f2b(b4[0]); v[5]=f2b(b4[1]); v[6]=f2b(b4[2]); v[7]=f2b(b4[3]);
      } else {
        v = *(const short8*)((const short*)Wsrc + ibase + (size_t)k * DOUT + n8);
      }
      #pragma unroll
      for (int jj = 0; jj < 8; ++jj) tile[k][n8 + jj] = (unsigned short)v[jj];
    }
    __syncthreads();
    size_t obase = (size_t)e * DOUT * DIN + (size_t)(nt * 64) * DIN + kt * 64;
    #pragma unroll
    for (int it = 0; it < 2; ++it) {
      int c = it * 256 + tid;
      int n = c >> 3, k8 = (c & 7) * 8;
      short8 o;
      #pragma unroll
      for (int jj = 0; jj < 8; ++jj) o[jj] = (short)tile[k8 + jj][n];
      *(short8*)(Wt + obase + (size_t)n * DIN + k8) = o;
    }
    return;
  }
  int mp = padoffG[NE];
  int rb = (blockIdx.x - TRANS_BLOCKS) * 4 + (tid >> 6);
  int lane = tid & 63;
  if (rb >= mp) return;
  int tok = tpad[rb];  // wave-uniform
  short8 v0 = {0, 0, 0, 0, 0, 0, 0, 0}, v1 = v0;
  if (tok >= 0) {
    if (fp32) {
      const float* xf = (const float*)xv + (size_t)tok * DIN + lane * 16;
      floatx4 a = *(const floatx4*)xf;
      floatx4 b = *(const floatx4*)(xf + 4);
      floatx4 c = *(const floatx4*)(xf + 8);
      floatx4 d = *(const floatx4*)(xf + 12);
      v0[0]=f2b(a[0]); v0[1]=f2b(a[1]); v0[2]=f2b(a[2]); v0[3]=f2b(a[3]);
      v0[4]=f2b(b[0]); v0[5]=f2b(b[1]); v0[6]=f2b(b[2]); v0[7]=f2b(b[3]);
      v1[0]=f2b(c[0]); v1[1]=f2b(c[1]); v1[2]=f2b(c[2]); v1[3]=f2b(c[3]);
      v1[4]=f2b(d[0]); v1[5]=f2b(d[1]); v1[6]=f2b(d[2]); v1[7]=f2b(d[3]);
    } else {
      const short* xs = (const short*)xv + (size_t)tok * DIN + lane * 16;
      v0 = *(const short8*)xs;
      v1 = *(const short8*)(xs + 8);
    }
  }
  short* dst = Aperm + (size_t)rb * DIN + lane * 16;
  *(short8*)dst = v0;
  *(short8*)(dst + 8) = v1;
}

// ---- GEMM: 128x64 tile, BK=32, grid 2176 (8 xcd x 16 nt x 17 ti).
// Operand-swapped MFMA (reg r <-> n contiguous) -> 8-B vector scatter stores.
__launch_bounds__(256, 6)
__global__ void k_gemm(const short* __restrict__ Aperm, const void* __restrict__ bv,
                       const short* __restrict__ Wt, const int* __restrict__ tpad,
                       const int* __restrict__ ntilesp, const int4v* __restrict__ table,
                       const int* __restrict__ flagp, void* __restrict__ outv) {
  int bid = blockIdx.x;
  int xcd = bid & 7;
  int s = bid >> 3;
  int nt = s & 15;
  int ti = s >> 4;                 // [0, TPX)
  int t = xcd * TPX + ti;          // contiguous A-tile range per XCD
  if (t >= *ntilesp) return;
  int4v te = table[t];
  int e = te.x, arow0 = te.y;
  int fp32 = *flagp;

  int tid = threadIdx.x;
  int lane = tid & 63;
  int wave = tid >> 6;

  __shared__ short lA[BM * BK];  // 8 KB dense [m][k]
  __shared__ short lB[BN * BK];  // 4 KB dense [n][k]
  __shared__ int tokS[BM];

  const short* WtE = Wt + (size_t)e * DOUT * DIN + (size_t)(nt * BN) * DIN;
  const short* aBase = Aperm + (size_t)arow0 * DIN;

  // A: 512 16B chunks (2/thread); B: 256 chunks (1/thread). fl: row=fl>>2, kc=fl&3
  const short* aG[2];
  char* aL[2];
  #pragma unroll
  for (int s4 = 0; s4 < 2; ++s4) {
    int fl = tid + s4 * 256;
    aG[s4] = aBase + (size_t)(fl >> 2) * DIN + (fl & 3) * 8;
    aL[s4] = (char*)lA + (s4 * 256 + wave * 64) * 16;
  }
  const short* bG = WtE + (size_t)(tid >> 2) * DIN + (tid & 3) * 8;
  char* bL = (char*)lB + wave * 64 * 16;

  int wm = wave & 1, wn = wave >> 1;          // wn in {0,1}
  int lrow = lane & 15, q = lane >> 4;
  int aOff[4], bOff[2];  // shorts
  #pragma unroll
  for (int i = 0; i < 4; ++i) aOff[i] = (wm * 64 + i * 16 + lrow) * BK + q * 8;
  #pragma unroll
  for (int j = 0; j < 2; ++j) bOff[j] = (wn * 32 + j * 16 + lrow) * BK + q * 8;

  floatx4 acc[4][2];
  #pragma unroll
  for (int i = 0; i < 4; ++i)
    #pragma unroll
    for (int j = 0; j < 2; ++j)
      acc[i][j] = (floatx4){0.f, 0.f, 0.f, 0.f};

  for (int k0 = 0; k0 < DIN; k0 += BK) {
    __syncthreads();
    glds16(bG + k0, bL);
    #pragma unroll
    for (int s4 = 0; s4 < 2; ++s4) glds16(aG[s4] + k0, aL[s4]);
    __syncthreads();
    short8 af[4], bf[2];
    #pragma unroll
    for (int i = 0; i < 4; ++i) af[i] = *(const short8*)(lA + aOff[i]);
    #pragma unroll
    for (int j = 0; j < 2; ++j) bf[j] = *(const short8*)(lB + bOff[j]);
    // SWAPPED: D[p][c] = sum_k Wt[n-frag p][k] * A[m-frag c][k]
    #pragma unroll
    for (int i = 0; i < 4; ++i)
      #pragma unroll
      for (int j = 0; j < 2; ++j)
        acc[i][j] = __builtin_amdgcn_mfma_f32_16x16x32_bf16(bf[j], af[i], acc[i][j], 0, 0, 0);
  }

  if (tid < BM) tokS[tid] = tpad[arow0 + tid];
  __syncthreads();

  // n = nt*64 + wn*32 + j*16 + q*4 + r (regs contiguous in n); m = wm*64+i*16+lrow
  float bias[2][4];
  #pragma unroll
  for (int j = 0; j < 2; ++j) {
    int n = nt * BN + wn * 32 + j * 16 + q * 4;
    if (fp32) {
      floatx4 b4 = *(const floatx4*)((const float*)bv + e * DOUT + n);
      #pragma unroll
      for (int r = 0; r < 4; ++r) bias[j][r] = b4[r];
    } else {
      short4v b4 = *(const short4v*)((const short*)bv + e * DOUT + n);
      #pragma unroll
      for (int r = 0; r < 4; ++r) bias[j][r] = b2f((unsigned short)b4[r]);
    }
  }
  #pragma unroll
  for (int i = 0; i < 4; ++i) {
    int tok = tokS[wm * 64 + i * 16 + lrow];
    if (tok < 0) continue;
    size_t rowb = (size_t)tok * DOUT + nt * BN + wn * 32 + q * 4;
    #pragma unroll
    for (int j = 0; j < 2; ++j) {
      if (fp32) {
        floatx4 o;
        #pragma unroll
        for (int r = 0; r < 4; ++r) {
          float v = acc[i][j][r] + bias[j][r];
          o[r] = v > 0.f ? v : 0.f;
        }
        *(floatx4*)((float*)outv + rowb + j * 16) = o;
      } else {
        short4v o;
        #pragma unroll
        for (int r = 0; r < 4; ++r) {
          float v = acc[i][j][r] + bias[j][r];
          o[r] = f2b(v > 0.f ? v : 0.f);
        }
        *(short4v*)((short*)outv + rowb + j * 16) = o;
      }
    }
  }
}

// ---- correct-but-slow fallback if ws too small
__global__ void k_fallback(const void* __restrict__ xv, const int* __restrict__ idxs,
                           const void* __restrict__ Wv, const void* __restrict__ bv,
                           void* __restrict__ outv) {
  __shared__ float xrow[DIN];
  __shared__ int sflag;
  int t = blockIdx.x;
  int e = idxs[t];
  if (threadIdx.x == 0) {
    const unsigned short* u = (const unsigned short*)xv;
    int f = 0;
    for (int i = 0; i < 256; ++i) { int ex = (u[i] >> 7) & 0xFF; if (ex >= 0xC0) f = 1; }
    sflag = f;
  }
  __syncthreads();
  int fp32 = sflag;
  for (int i = threadIdx.x; i < DIN; i += 256)
    xrow[i] = fp32 ? ((const float*)xv)[(size_t)t * DIN + i]
                   : b2f(((const unsigned short*)xv)[(size_t)t * DIN + i]);
  __syncthreads();
  float a[4] = {0.f, 0.f, 0.f, 0.f};
  for (int k = 0; k < DIN; ++k) {
    float xk = xrow[k];
    size_t wb = (size_t)e * DIN * DOUT + (size_t)k * DOUT + threadIdx.x;
    #pragma unroll
    for (int j = 0; j < 4; ++j) {
      float w = fp32 ? ((const float*)Wv)[wb + j * 256]
                     : b2f(((const unsigned short*)Wv)[wb + j * 256]);
      a[j] += xk * w;
    }
  }
  #pragma unroll
  for (int j = 0; j < 4; ++j) {
    int n = threadIdx.x + j * 256;
    float bias = fp32 ? ((const float*)bv)[e * DOUT + n]
                      : b2f(((const unsigned short*)bv)[e * DOUT + n]);
    float v = a[j] + bias;
    v = v > 0.f ? v : 0.f;
    size_t o = (size_t)t * DOUT + n;
    if (fp32) ((float*)outv)[o] = v;
    else      ((short*)outv)[o] = f2b(v);
  }
}

extern "C" void kernel_launch(void* const* d_in, const int* in_sizes, int n_in,
                              void* d_out, int out_size, void* d_ws, size_t ws_size,
                              hipStream_t stream) {
  const void* x    = d_in[0];
  const int*  idxs = (const int*)d_in[1];
  const void* W    = d_in[2];
  const void* bias = d_in[3];

  if (ws_size < WS_NEED) {
    k_fallback<<<T_TOK, 256, 0, stream>>>(x, idxs, W, bias, d_out);
    return;
  }
  char* ws = (char*)d_ws;
  int* flag    = (int*)(ws + FLAG_OFF);
  int* ntiles  = (int*)(ws + NTILES_OFF);
  int* counts  = (int*)(ws + COUNTS_OFF);
  int* cursor  = (int*)(ws + CURSOR_OFF);
  int* padoff  = (int*)(ws + PADOFF_OFF);
  int4v* table = (int4v*)(ws + TABLE_OFF);
  int* tpad    = (int*)(ws + TPAD_OFF);
  short* Wt    = (short*)(ws + WT_OFF);
  short* Aperm = (short*)(ws + APERM_OFF);

  k_prep<<<1, 1024, 0, stream>>>((const unsigned short*)x, idxs, flag, cursor,
                                 counts, padoff, ntiles, table, tpad);
  k_scatter<<<T_TOK / 256, 256, 0, stream>>>(idxs, padoff, cursor, tpad);
  k_stage<<<TRANS_BLOCKS + GATHER_BLOCKS, 256, 0, stream>>>(
      W, Wt, x, Aperm, padoff, tpad, flag);
  k_gemm<<<8 * 16 * TPX, 256, 0, stream>>>(Aperm, bias, Wt, tpad, ntiles, table, flag, d_out);
}

// Round 5
// 270.204 us; speedup vs baseline: 1.2352x; 1.0575x over previous
//
#include <hip/hip_runtime.h>
#include <hip/hip_bf16.h>
#include <stdint.h>

// MoE grouped linear: y[t] = relu(x[t] @ W[idxs[t]] + b[idxs[t]])
// T=16384, D_IN=D_OUT=1024, E=8.
// R5: GEMM BK=64 (16 iters -> halved barrier/drain fixed cost) + XOR-swizzled
// 16B chunks (phys = logical ^ (row&7), applied on the global-source side so
// glds LDS dst stays wave-uniform) -> minimum-aliasing b128 frag reads.
// Keeps: BN=64 grid 2176, XCD swizzle (R3), operand-swapped epilogue (R3/R4).

#define T_TOK 16384
#define DIN   1024
#define DOUT  1024
#define NE    8
#define BM    128
#define BN    64
#define BK    64
#define TPX   17                  // A-tiles per XCD slot (8*17 = 136)
#define MAX_TILES 136
#define MP_MAX (T_TOK + NE * BM)  // 17408 padded rows max

typedef __attribute__((ext_vector_type(8))) short short8;
typedef __attribute__((ext_vector_type(4))) short short4v;
typedef __attribute__((ext_vector_type(4))) float floatx4;
typedef __attribute__((ext_vector_type(4))) int int4v;

__device__ __forceinline__ short f2b(float f) {
  return __builtin_bit_cast(short, __float2bfloat16(f));
}
__device__ __forceinline__ float b2f(unsigned short u) {
  unsigned v = ((unsigned)u) << 16;
  return __builtin_bit_cast(float, v);
}
__device__ __forceinline__ void glds16(const void* g, void* l) {
  __builtin_amdgcn_global_load_lds(
      (__attribute__((address_space(1))) void*)g,
      (__attribute__((address_space(3))) void*)l, 16, 0, 0);
}

// ws layout (bytes)
#define FLAG_OFF    0
#define NTILES_OFF  64
#define COUNTS_OFF  128
#define CURSOR_OFF  384
#define PADOFF_OFF  512   // 9 ints
#define TABLE_OFF   1024  // MAX_TILES * int4
#define TPAD_OFF    4096  // MP_MAX ints (token id per padded row, -1 = pad)
#define WT_OFF      73728 // 16 MB bf16 [E][n][k]
#define APERM_OFF   16850944
#define WS_NEED     (16850944UL + (size_t)MP_MAX * DIN * 2)

// ---- fused prep: dtype detect + histogram + scan + tile table + tpad=-1 init.
__global__ void k_prep(const unsigned short* __restrict__ x, const int* __restrict__ idxs,
                       int* __restrict__ flag, int* __restrict__ cursor,
                       int* __restrict__ countsG, int* __restrict__ padoffG,
                       int* __restrict__ ntiles, int4v* __restrict__ table,
                       int* __restrict__ tpad) {
  __shared__ int hist[16][9];
  int tid = threadIdx.x;
  if (tid < 16 * 9) ((int*)hist)[tid] = 0;
  int f = 0;
  if (tid < 64) {
    #pragma unroll
    for (int i = 0; i < 4; ++i) {
      int ex = (x[tid * 4 + i] >> 7) & 0xFF;
      if (ex >= 0xC0) f = 1;
    }
  }
  unsigned long long any = __ballot(f);
  if (tid == 0) *flag = any ? 1 : 0;
  if (tid < NE) cursor[tid] = 0;
  __syncthreads();
  int sub = tid >> 6;
  const int4v* iv = (const int4v*)idxs;
  #pragma unroll
  for (int it = 0; it < 4; ++it) {
    int4v v = iv[it * 1024 + tid];
    atomicAdd(&hist[sub][v.x], 1);
    atomicAdd(&hist[sub][v.y], 1);
    atomicAdd(&hist[sub][v.z], 1);
    atomicAdd(&hist[sub][v.w], 1);
  }
  __syncthreads();
  if (tid == 0) {
    int p = 0, tc = 0;
    for (int e = 0; e < NE; ++e) {
      int c = 0;
      for (int s = 0; s < 16; ++s) c += hist[s][e];
      countsG[e] = c;
      padoffG[e] = p;
      int nmt = (c + BM - 1) / BM;
      for (int m = 0; m < nmt; ++m) table[tc++] = (int4v){e, p + m * BM, 0, 0};
      p += nmt * BM;
    }
    padoffG[NE] = p;
    *ntiles = tc;
  }
  const int4v neg = (int4v){-1, -1, -1, -1};
  #pragma unroll
  for (int it = 0; it < 5; ++it) {
    int idx = it * 1024 + tid;
    if (idx < MP_MAX / 4) ((int4v*)tpad)[idx] = neg;
  }
}

// ---- scatter tokens directly into padded slots
__global__ void k_scatter(const int* __restrict__ idxs, const int* __restrict__ padoffG,
                          int* __restrict__ cursor, int* __restrict__ tpad) {
  int t = blockIdx.x * 256 + threadIdx.x;
  int e = idxs[t];
  int p = atomicAdd(&cursor[e], 1);
  tpad[padoffG[e] + p] = t;
}

// ---- fused staging: blocks [0,2048): W [E][k][n] -> Wt [E][n][k] bf16;
//      blocks [2048,..): gather x rows (permuted, padded, bf16) -> Aperm
#define TRANS_BLOCKS (NE * 16 * 16)
#define GATHER_BLOCKS (MP_MAX / 4)
__global__ void k_stage(const void* __restrict__ Wsrc, short* __restrict__ Wt,
                        const void* __restrict__ xv, short* __restrict__ Aperm,
                        const int* __restrict__ padoffG, const int* __restrict__ tpad,
                        const int* __restrict__ flagp) {
  int tid = threadIdx.x;
  int fp32 = *flagp;
  if (blockIdx.x < TRANS_BLOCKS) {
    __shared__ unsigned short tile[64][66];
    int b = blockIdx.x;
    int e = b >> 8;
    int kt = (b >> 4) & 15;
    int nt = b & 15;
    size_t ibase = (size_t)e * DIN * DOUT + (size_t)(kt * 64) * DOUT + nt * 64;
    #pragma unroll
    for (int it = 0; it < 2; ++it) {
      int c = it * 256 + tid;
      int k = c >> 3, n8 = (c & 7) * 8;
      short8 v;
      if (fp32) {
        const float* p = (const float*)Wsrc + ibase + (size_t)k * DOUT + n8;
        floatx4 a = *(const floatx4*)p;
        floatx4 b4 = *(const floatx4*)(p + 4);
        v[0]=f2b(a[0]); v[1]=f2b(a[1]); v[2]=f2b(a[2]); v[3]=f2b(a[3]);
        v[4]=f2b(b4[0]); v[5]=f2b(b4[1]); v[6]=f2b(b4[2]); v[7]=f2b(b4[3]);
      } else {
        v = *(const short8*)((const short*)Wsrc + ibase + (size_t)k * DOUT + n8);
      }
      #pragma unroll
      for (int jj = 0; jj < 8; ++jj) tile[k][n8 + jj] = (unsigned short)v[jj];
    }
    __syncthreads();
    size_t obase = (size_t)e * DOUT * DIN + (size_t)(nt * 64) * DIN + kt * 64;
    #pragma unroll
    for (int it = 0; it < 2; ++it) {
      int c = it * 256 + tid;
      int n = c >> 3, k8 = (c & 7) * 8;
      short8 o;
      #pragma unroll
      for (int jj = 0; jj < 8; ++jj) o[jj] = (short)tile[k8 + jj][n];
      *(short8*)(Wt + obase + (size_t)n * DIN + k8) = o;
    }
    return;
  }
  int mp = padoffG[NE];
  int rb = (blockIdx.x - TRANS_BLOCKS) * 4 + (tid >> 6);
  int lane = tid & 63;
  if (rb >= mp) return;
  int tok = tpad[rb];  // wave-uniform
  short8 v0 = {0, 0, 0, 0, 0, 0, 0, 0}, v1 = v0;
  if (tok >= 0) {
    if (fp32) {
      const float* xf = (const float*)xv + (size_t)tok * DIN + lane * 16;
      floatx4 a = *(const floatx4*)xf;
      floatx4 b = *(const floatx4*)(xf + 4);
      floatx4 c = *(const floatx4*)(xf + 8);
      floatx4 d = *(const floatx4*)(xf + 12);
      v0[0]=f2b(a[0]); v0[1]=f2b(a[1]); v0[2]=f2b(a[2]); v0[3]=f2b(a[3]);
      v0[4]=f2b(b[0]); v0[5]=f2b(b[1]); v0[6]=f2b(b[2]); v0[7]=f2b(b[3]);
      v1[0]=f2b(c[0]); v1[1]=f2b(c[1]); v1[2]=f2b(c[2]); v1[3]=f2b(c[3]);
      v1[4]=f2b(d[0]); v1[5]=f2b(d[1]); v1[6]=f2b(d[2]); v1[7]=f2b(d[3]);
    } else {
      const short* xs = (const short*)xv + (size_t)tok * DIN + lane * 16;
      v0 = *(const short8*)xs;
      v1 = *(const short8*)(xs + 8);
    }
  }
  short* dst = Aperm + (size_t)rb * DIN + lane * 16;
  *(short8*)dst = v0;
  *(short8*)(dst + 8) = v1;
}

// ---- GEMM: 128x64 tile, BK=64 (16 iters), XOR-swizzled LDS chunks.
// LDS layout: row r (128B = 8 chunks of 16B), phys chunk p holds logical
// chunk p^(r&7). Staging permutes the GLOBAL source (glds dst stays uniform).
// Operand-swapped MFMA (reg r <-> n contiguous) -> 8-B vector scatter stores.
__launch_bounds__(256, 6)
__global__ void k_gemm(const short* __restrict__ Aperm, const void* __restrict__ bv,
                       const short* __restrict__ Wt, const int* __restrict__ tpad,
                       const int* __restrict__ ntilesp, const int4v* __restrict__ table,
                       const int* __restrict__ flagp, void* __restrict__ outv) {
  int bid = blockIdx.x;
  int xcd = bid & 7;
  int s = bid >> 3;
  int nt = s & 15;
  int ti = s >> 4;                 // [0, TPX)
  int t = xcd * TPX + ti;          // contiguous A-tile range per XCD
  if (t >= *ntilesp) return;
  int4v te = table[t];
  int e = te.x, arow0 = te.y;
  int fp32 = *flagp;

  int tid = threadIdx.x;
  int lane = tid & 63;
  int wave = tid >> 6;

  __shared__ short lA[BM * BK];  // 16 KB, rows of 128B (8 chunks), swizzled
  __shared__ short lB[BN * BK];  // 8 KB
  __shared__ int tokS[BM];

  const short* WtE = Wt + (size_t)e * DOUT * DIN + (size_t)(nt * BN) * DIN;
  const short* aBase = Aperm + (size_t)arow0 * DIN;

  // A: 1024 chunks (4/thread); B: 512 chunks (2/thread).
  // phys chunk fl: r = fl>>3, p = fl&7; global logical chunk kc = p ^ (r&7).
  const short* aG[4];
  char* aL[4];
  #pragma unroll
  for (int s4 = 0; s4 < 4; ++s4) {
    int fl = tid + s4 * 256;
    int r = fl >> 3, p = fl & 7;
    int kc = p ^ (r & 7);
    aG[s4] = aBase + (size_t)r * DIN + kc * 8;
    aL[s4] = (char*)lA + (s4 * 256 + wave * 64) * 16;
  }
  const short* bG[2];
  char* bL[2];
  #pragma unroll
  for (int s4 = 0; s4 < 2; ++s4) {
    int fl = tid + s4 * 256;
    int r = fl >> 3, p = fl & 7;
    int kc = p ^ (r & 7);
    bG[s4] = WtE + (size_t)r * DIN + kc * 8;
    bL[s4] = (char*)lB + (s4 * 256 + wave * 64) * 16;
  }

  int wm = wave & 1, wn = wave >> 1;          // wn in {0,1}
  int lrow = lane & 15, q = lane >> 4;
  // frag reads: logical chunk c = h*4+q of row m -> phys addr m*64 + (c^(m&7))*8 shorts
  int aOff[4][2], bOff[2][2];
  #pragma unroll
  for (int i = 0; i < 4; ++i) {
    int m = wm * 64 + i * 16 + lrow;
    #pragma unroll
    for (int h = 0; h < 2; ++h)
      aOff[i][h] = m * BK + (((h * 4 + q) ^ (m & 7)) * 8);
  }
  #pragma unroll
  for (int j = 0; j < 2; ++j) {
    int n = wn * 32 + j * 16 + lrow;
    #pragma unroll
    for (int h = 0; h < 2; ++h)
      bOff[j][h] = n * BK + (((h * 4 + q) ^ (n & 7)) * 8);
  }

  floatx4 acc[4][2];
  #pragma unroll
  for (int i = 0; i < 4; ++i)
    #pragma unroll
    for (int j = 0; j < 2; ++j)
      acc[i][j] = (floatx4){0.f, 0.f, 0.f, 0.f};

  for (int k0 = 0; k0 < DIN; k0 += BK) {
    __syncthreads();
    #pragma unroll
    for (int s4 = 0; s4 < 2; ++s4) glds16(bG[s4] + k0, bL[s4]);
    #pragma unroll
    for (int s4 = 0; s4 < 4; ++s4) glds16(aG[s4] + k0, aL[s4]);
    __syncthreads();
    #pragma unroll
    for (int h = 0; h < 2; ++h) {
      short8 af[4], bf[2];
      #pragma unroll
      for (int i = 0; i < 4; ++i) af[i] = *(const short8*)(lA + aOff[i][h]);
      #pragma unroll
      for (int j = 0; j < 2; ++j) bf[j] = *(const short8*)(lB + bOff[j][h]);
      // SWAPPED: D[p][c] = sum_k Wt[n-frag p][k] * A[m-frag c][k]
      #pragma unroll
      for (int i = 0; i < 4; ++i)
        #pragma unroll
        for (int j = 0; j < 2; ++j)
          acc[i][j] = __builtin_amdgcn_mfma_f32_16x16x32_bf16(bf[j], af[i], acc[i][j], 0, 0, 0);
    }
  }

  if (tid < BM) tokS[tid] = tpad[arow0 + tid];
  __syncthreads();

  // n = nt*64 + wn*32 + j*16 + q*4 + r (regs contiguous in n); m = wm*64+i*16+lrow
  float bias[2][4];
  #pragma unroll
  for (int j = 0; j < 2; ++j) {
    int n = nt * BN + wn * 32 + j * 16 + q * 4;
    if (fp32) {
      floatx4 b4 = *(const floatx4*)((const float*)bv + e * DOUT + n);
      #pragma unroll
      for (int r = 0; r < 4; ++r) bias[j][r] = b4[r];
    } else {
      short4v b4 = *(const short4v*)((const short*)bv + e * DOUT + n);
      #pragma unroll
      for (int r = 0; r < 4; ++r) bias[j][r] = b2f((unsigned short)b4[r]);
    }
  }
  #pragma unroll
  for (int i = 0; i < 4; ++i) {
    int tok = tokS[wm * 64 + i * 16 + lrow];
    if (tok < 0) continue;
    size_t rowb = (size_t)tok * DOUT + nt * BN + wn * 32 + q * 4;
    #pragma unroll
    for (int j = 0; j < 2; ++j) {
      if (fp32) {
        floatx4 o;
        #pragma unroll
        for (int r = 0; r < 4; ++r) {
          float v = acc[i][j][r] + bias[j][r];
          o[r] = v > 0.f ? v : 0.f;
        }
        *(floatx4*)((float*)outv + rowb + j * 16) = o;
      } else {
        short4v o;
        #pragma unroll
        for (int r = 0; r < 4; ++r) {
          float v = acc[i][j][r] + bias[j][r];
          o[r] = f2b(v > 0.f ? v : 0.f);
        }
        *(short4v*)((short*)outv + rowb + j * 16) = o;
      }
    }
  }
}

// ---- correct-but-slow fallback if ws too small
__global__ void k_fallback(const void* __restrict__ xv, const int* __restrict__ idxs,
                           const void* __restrict__ Wv, const void* __restrict__ bv,
                           void* __restrict__ outv) {
  __shared__ float xrow[DIN];
  __shared__ int sflag;
  int t = blockIdx.x;
  int e = idxs[t];
  if (threadIdx.x == 0) {
    const unsigned short* u = (const unsigned short*)xv;
    int f = 0;
    for (int i = 0; i < 256; ++i) { int ex = (u[i] >> 7) & 0xFF; if (ex >= 0xC0) f = 1; }
    sflag = f;
  }
  __syncthreads();
  int fp32 = sflag;
  for (int i = threadIdx.x; i < DIN; i += 256)
    xrow[i] = fp32 ? ((const float*)xv)[(size_t)t * DIN + i]
                   : b2f(((const unsigned short*)xv)[(size_t)t * DIN + i]);
  __syncthreads();
  float a[4] = {0.f, 0.f, 0.f, 0.f};
  for (int k = 0; k < DIN; ++k) {
    float xk = xrow[k];
    size_t wb = (size_t)e * DIN * DOUT + (size_t)k * DOUT + threadIdx.x;
    #pragma unroll
    for (int j = 0; j < 4; ++j) {
      float w = fp32 ? ((const float*)Wv)[wb + j * 256]
                     : b2f(((const unsigned short*)Wv)[wb + j * 256]);
      a[j] += xk * w;
    }
  }
  #pragma unroll
  for (int j = 0; j < 4; ++j) {
    int n = threadIdx.x + j * 256;
    float bias = fp32 ? ((const float*)bv)[e * DOUT + n]
                      : b2f(((const unsigned short*)bv)[e * DOUT + n]);
    float v = a[j] + bias;
    v = v > 0.f ? v : 0.f;
    size_t o = (size_t)t * DOUT + n;
    if (fp32) ((float*)outv)[o] = v;
    else      ((short*)outv)[o] = f2b(v);
  }
}

extern "C" void kernel_launch(void* const* d_in, const int* in_sizes, int n_in,
                              void* d_out, int out_size, void* d_ws, size_t ws_size,
                              hipStream_t stream) {
  const void* x    = d_in[0];
  const int*  idxs = (const int*)d_in[1];
  const void* W    = d_in[2];
  const void* bias = d_in[3];

  if (ws_size < WS_NEED) {
    k_fallback<<<T_TOK, 256, 0, stream>>>(x, idxs, W, bias, d_out);
    return;
  }
  char* ws = (char*)d_ws;
  int* flag    = (int*)(ws + FLAG_OFF);
  int* ntiles  = (int*)(ws + NTILES_OFF);
  int* counts  = (int*)(ws + COUNTS_OFF);
  int* cursor  = (int*)(ws + CURSOR_OFF);
  int* padoff  = (int*)(ws + PADOFF_OFF);
  int4v* table = (int4v*)(ws + TABLE_OFF);
  int* tpad    = (int*)(ws + TPAD_OFF);
  short* Wt    = (short*)(ws + WT_OFF);
  short* Aperm = (short*)(ws + APERM_OFF);

  k_prep<<<1, 1024, 0, stream>>>((const unsigned short*)x, idxs, flag, cursor,
                                 counts, padoff, ntiles, table, tpad);
  k_scatter<<<T_TOK / 256, 256, 0, stream>>>(idxs, padoff, cursor, tpad);
  k_stage<<<TRANS_BLOCKS + GATHER_BLOCKS, 256, 0, stream>>>(
      W, Wt, x, Aperm, padoff, tpad, flag);
  k_gemm<<<8 * 16 * TPX, 256, 0, stream>>>(Aperm, bias, Wt, tpad, ntiles, table, flag, d_out);
}

// Round 6
// 210.109 us; speedup vs baseline: 1.5885x; 1.2860x over previous
//
#include <hip/hip_runtime.h>
#include <hip/hip_bf16.h>
#include <stdint.h>

// MoE grouped linear: y[t] = relu(x[t] @ W[idxs[t]] + b[idxs[t]])
// T=16384, D_IN=D_OUT=1024, E=8.
// R6: atomic-free bucketing. k_scatter was 63.7us of pure atomic contention
// (16384 atomicAdds on 8 addresses). Now: prep computes deterministic
// blockBase[64][8] via shuffle-scan; scatter ranks via ballot+popcount.
// GEMM unchanged from R5 (BK=64, XOR-swizzled LDS, operand-swapped epilogue).

#define T_TOK 16384
#define DIN   1024
#define DOUT  1024
#define NE    8
#define BM    128
#define BN    64
#define BK    64
#define TPX   17                  // A-tiles per XCD slot (8*17 = 136)
#define MAX_TILES 136
#define MP_MAX (T_TOK + NE * BM)  // 17408 padded rows max

typedef __attribute__((ext_vector_type(8))) short short8;
typedef __attribute__((ext_vector_type(4))) short short4v;
typedef __attribute__((ext_vector_type(4))) float floatx4;
typedef __attribute__((ext_vector_type(4))) int int4v;

__device__ __forceinline__ short f2b(float f) {
  return __builtin_bit_cast(short, __float2bfloat16(f));
}
__device__ __forceinline__ float b2f(unsigned short u) {
  unsigned v = ((unsigned)u) << 16;
  return __builtin_bit_cast(float, v);
}
__device__ __forceinline__ void glds16(const void* g, void* l) {
  __builtin_amdgcn_global_load_lds(
      (__attribute__((address_space(1))) void*)g,
      (__attribute__((address_space(3))) void*)l, 16, 0, 0);
}

// ws layout (bytes)
#define FLAG_OFF    0
#define NTILES_OFF  64
#define COUNTS_OFF  128
#define PADOFF_OFF  512    // 9 ints
#define BB_OFF      1024   // blockBase[64][8] ints (2048 B)
#define TABLE_OFF   4096   // MAX_TILES * int4 (2176 B)
#define TPAD_OFF    8192   // MP_MAX ints
#define WT_OFF      81920  // 16 MB bf16 [E][n][k]
#define APERM_OFF   16859136
#define WS_NEED     (16859136UL + (size_t)MP_MAX * DIN * 2)

// ---- prep: dtype detect + per-(scatter-block, expert) base offsets via
// hierarchical scan + padoff/table + pad-slot fill. 1 block x 1024 threads;
// thread tid covers tokens [tid*16, tid*16+16).
__global__ void k_prep(const unsigned short* __restrict__ x, const int* __restrict__ idxs,
                       int* __restrict__ flag, int* __restrict__ countsG,
                       int* __restrict__ padoffG, int* __restrict__ ntiles,
                       int4v* __restrict__ table, int* __restrict__ blockBase,
                       int* __restrict__ tpad) {
  __shared__ int wtot[16][NE];      // per-wave expert totals
  __shared__ int waveBase[16][NE];  // padoff[e] + tokens before wave w
  __shared__ int totS[NE], padS[NE + 1];
  int tid = threadIdx.x;
  int lane = tid & 63, w = tid >> 6;

  if (tid < 64) {  // wave 0 fully active: ballot is wave-wide
    int f = 0;
    #pragma unroll
    for (int i = 0; i < 4; ++i) {
      int ex = (x[tid * 4 + i] >> 7) & 0xFF;
      if (ex >= 0xC0) f = 1;
    }
    unsigned long long any = __ballot(f);
    if (tid == 0) *flag = any ? 1 : 0;
  }

  int c[NE];
  #pragma unroll
  for (int e = 0; e < NE; ++e) c[e] = 0;
  const int4v* iv = (const int4v*)idxs;
  #pragma unroll
  for (int it = 0; it < 4; ++it) {
    int4v v = iv[tid * 4 + it];
    ++c[v.x]; ++c[v.y]; ++c[v.z]; ++c[v.w];
  }
  // wave-level inclusive scan per expert
  int incl[NE];
  #pragma unroll
  for (int e = 0; e < NE; ++e) {
    incl[e] = c[e];
    #pragma unroll
    for (int d = 1; d < 64; d <<= 1) {
      int o = __shfl_up(incl[e], d);
      if (lane >= d) incl[e] += o;
    }
  }
  if (lane == 63) {
    #pragma unroll
    for (int e = 0; e < NE; ++e) wtot[w][e] = incl[e];
  }
  __syncthreads();
  if (tid < NE) {
    int s = 0;
    for (int ww = 0; ww < 16; ++ww) s += wtot[ww][tid];
    totS[tid] = s;
    countsG[tid] = s;
  }
  __syncthreads();
  if (tid == 0) {
    int p = 0, tc = 0;
    for (int e = 0; e < NE; ++e) {
      padS[e] = p;
      padoffG[e] = p;
      int cn = totS[e];
      int nmt = (cn + BM - 1) >> 7;
      for (int m = 0; m < nmt; ++m) table[tc++] = (int4v){e, p + m * BM, 0, 0};
      p += nmt * BM;
    }
    padS[NE] = p;
    padoffG[NE] = p;
    *ntiles = tc;
  }
  __syncthreads();
  if (tid < 128) {
    int ww = tid >> 3, e = tid & 7;
    int s = padS[e];
    for (int wp = 0; wp < ww; ++wp) s += wtot[wp][e];
    waveBase[ww][e] = s;
  }
  __syncthreads();
  if ((tid & 15) == 0) {
    int B = tid >> 4;  // scatter-block id; token B*256 == tid*16
    #pragma unroll
    for (int e = 0; e < NE; ++e)
      blockBase[B * NE + e] = waveBase[w][e] + (incl[e] - c[e]);
  }
  // pad slots: [padS[e]+totS[e], padS[e+1]) = -1 (len < 128 each)
  #pragma unroll
  for (int e = 0; e < NE; ++e) {
    int start = padS[e] + totS[e];
    int len = padS[e + 1] - start;
    if (tid < len) tpad[start + tid] = -1;
  }
}

// ---- scatter: deterministic, atomic-free. rank = ballot-popcount within wave
// + LDS cross-wave prefix + blockBase.
__global__ void k_scatter(const int* __restrict__ idxs, const int* __restrict__ blockBase,
                          int* __restrict__ tpad) {
  __shared__ int wc[4][NE], wexcl[4][NE];
  int b = blockIdx.x, tid = threadIdx.x;
  int lane = tid & 63, w = tid >> 6;
  int t = b * 256 + tid;
  int e = idxs[t];
  unsigned long long mymask = 0;
  #pragma unroll
  for (int e0 = 0; e0 < NE; ++e0) {
    unsigned long long m = __ballot(e == e0);
    if (lane == 0) wc[w][e0] = __popcll(m);
    if (e0 == e) mymask = m;
  }
  int rw = __popcll(mymask & ((1ull << lane) - 1ull));
  __syncthreads();
  if (tid < 32) {
    int ww = tid >> 3, e0 = tid & 7;
    int s = 0;
    for (int wp = 0; wp < ww; ++wp) s += wc[wp][e0];
    wexcl[ww][e0] = s;
  }
  __syncthreads();
  tpad[blockBase[b * NE + e] + wexcl[w][e] + rw] = t;
}

// ---- fused staging: blocks [0,2048): W [E][k][n] -> Wt [E][n][k] bf16;
//      blocks [2048,..): gather x rows (permuted, padded, bf16) -> Aperm
#define TRANS_BLOCKS (NE * 16 * 16)
#define GATHER_BLOCKS (MP_MAX / 4)
__global__ void k_stage(const void* __restrict__ Wsrc, short* __restrict__ Wt,
                        const void* __restrict__ xv, short* __restrict__ Aperm,
                        const int* __restrict__ padoffG, const int* __restrict__ tpad,
                        const int* __restrict__ flagp) {
  int tid = threadIdx.x;
  int fp32 = *flagp;
  if (blockIdx.x < TRANS_BLOCKS) {
    __shared__ unsigned short tile[64][66];
    int b = blockIdx.x;
    int e = b >> 8;
    int kt = (b >> 4) & 15;
    int nt = b & 15;
    size_t ibase = (size_t)e * DIN * DOUT + (size_t)(kt * 64) * DOUT + nt * 64;
    #pragma unroll
    for (int it = 0; it < 2; ++it) {
      int c = it * 256 + tid;
      int k = c >> 3, n8 = (c & 7) * 8;
      short8 v;
      if (fp32) {
        const float* p = (const float*)Wsrc + ibase + (size_t)k * DOUT + n8;
        floatx4 a = *(const floatx4*)p;
        floatx4 b4 = *(const floatx4*)(p + 4);
        v[0]=f2b(a[0]); v[1]=f2b(a[1]); v[2]=f2b(a[2]); v[3]=f2b(a[3]);
        v[4]=f2b(b4[0]); v[5]=f2b(b4[1]); v[6]=f2b(b4[2]); v[7]=f2b(b4[3]);
      } else {
        v = *(const short8*)((const short*)Wsrc + ibase + (size_t)k * DOUT + n8);
      }
      #pragma unroll
      for (int jj = 0; jj < 8; ++jj) tile[k][n8 + jj] = (unsigned short)v[jj];
    }
    __syncthreads();
    size_t obase = (size_t)e * DOUT * DIN + (size_t)(nt * 64) * DIN + kt * 64;
    #pragma unroll
    for (int it = 0; it < 2; ++it) {
      int c = it * 256 + tid;
      int n = c >> 3, k8 = (c & 7) * 8;
      short8 o;
      #pragma unroll
      for (int jj = 0; jj < 8; ++jj) o[jj] = (short)tile[k8 + jj][n];
      *(short8*)(Wt + obase + (size_t)n * DIN + k8) = o;
    }
    return;
  }
  int mp = padoffG[NE];
  int rb = (blockIdx.x - TRANS_BLOCKS) * 4 + (tid >> 6);
  int lane = tid & 63;
  if (rb >= mp) return;
  int tok = tpad[rb];  // wave-uniform
  short8 v0 = {0, 0, 0, 0, 0, 0, 0, 0}, v1 = v0;
  if (tok >= 0) {
    if (fp32) {
      const float* xf = (const float*)xv + (size_t)tok * DIN + lane * 16;
      floatx4 a = *(const floatx4*)xf;
      floatx4 b = *(const floatx4*)(xf + 4);
      floatx4 c = *(const floatx4*)(xf + 8);
      floatx4 d = *(const floatx4*)(xf + 12);
      v0[0]=f2b(a[0]); v0[1]=f2b(a[1]); v0[2]=f2b(a[2]); v0[3]=f2b(a[3]);
      v0[4]=f2b(b[0]); v0[5]=f2b(b[1]); v0[6]=f2b(b[2]); v0[7]=f2b(b[3]);
      v1[0]=f2b(c[0]); v1[1]=f2b(c[1]); v1[2]=f2b(c[2]); v1[3]=f2b(c[3]);
      v1[4]=f2b(d[0]); v1[5]=f2b(d[1]); v1[6]=f2b(d[2]); v1[7]=f2b(d[3]);
    } else {
      const short* xs = (const short*)xv + (size_t)tok * DIN + lane * 16;
      v0 = *(const short8*)xs;
      v1 = *(const short8*)(xs + 8);
    }
  }
  short* dst = Aperm + (size_t)rb * DIN + lane * 16;
  *(short8*)dst = v0;
  *(short8*)(dst + 8) = v1;
}

// ---- GEMM: 128x64 tile, BK=64 (16 iters), XOR-swizzled LDS chunks.
// LDS layout: row r (128B = 8 chunks of 16B), phys chunk p holds logical
// chunk p^(r&7). Staging permutes the GLOBAL source (glds dst stays uniform).
// Operand-swapped MFMA (reg r <-> n contiguous) -> 8-B vector scatter stores.
__launch_bounds__(256, 6)
__global__ void k_gemm(const short* __restrict__ Aperm, const void* __restrict__ bv,
                       const short* __restrict__ Wt, const int* __restrict__ tpad,
                       const int* __restrict__ ntilesp, const int4v* __restrict__ table,
                       const int* __restrict__ flagp, void* __restrict__ outv) {
  int bid = blockIdx.x;
  int xcd = bid & 7;
  int s = bid >> 3;
  int nt = s & 15;
  int ti = s >> 4;                 // [0, TPX)
  int t = xcd * TPX + ti;          // contiguous A-tile range per XCD
  if (t >= *ntilesp) return;
  int4v te = table[t];
  int e = te.x, arow0 = te.y;
  int fp32 = *flagp;

  int tid = threadIdx.x;
  int lane = tid & 63;
  int wave = tid >> 6;

  __shared__ short lA[BM * BK];  // 16 KB, rows of 128B (8 chunks), swizzled
  __shared__ short lB[BN * BK];  // 8 KB
  __shared__ int tokS[BM];

  const short* WtE = Wt + (size_t)e * DOUT * DIN + (size_t)(nt * BN) * DIN;
  const short* aBase = Aperm + (size_t)arow0 * DIN;

  // A: 1024 chunks (4/thread); B: 512 chunks (2/thread).
  // phys chunk fl: r = fl>>3, p = fl&7; global logical chunk kc = p ^ (r&7).
  const short* aG[4];
  char* aL[4];
  #pragma unroll
  for (int s4 = 0; s4 < 4; ++s4) {
    int fl = tid + s4 * 256;
    int r = fl >> 3, p = fl & 7;
    int kc = p ^ (r & 7);
    aG[s4] = aBase + (size_t)r * DIN + kc * 8;
    aL[s4] = (char*)lA + (s4 * 256 + wave * 64) * 16;
  }
  const short* bG[2];
  char* bL[2];
  #pragma unroll
  for (int s4 = 0; s4 < 2; ++s4) {
    int fl = tid + s4 * 256;
    int r = fl >> 3, p = fl & 7;
    int kc = p ^ (r & 7);
    bG[s4] = WtE + (size_t)r * DIN + kc * 8;
    bL[s4] = (char*)lB + (s4 * 256 + wave * 64) * 16;
  }

  int wm = wave & 1, wn = wave >> 1;          // wn in {0,1}
  int lrow = lane & 15, q = lane >> 4;
  // frag reads: logical chunk c = h*4+q of row m -> phys addr m*64 + (c^(m&7))*8 shorts
  int aOff[4][2], bOff[2][2];
  #pragma unroll
  for (int i = 0; i < 4; ++i) {
    int m = wm * 64 + i * 16 + lrow;
    #pragma unroll
    for (int h = 0; h < 2; ++h)
      aOff[i][h] = m * BK + (((h * 4 + q) ^ (m & 7)) * 8);
  }
  #pragma unroll
  for (int j = 0; j < 2; ++j) {
    int n = wn * 32 + j * 16 + lrow;
    #pragma unroll
    for (int h = 0; h < 2; ++h)
      bOff[j][h] = n * BK + (((h * 4 + q) ^ (n & 7)) * 8);
  }

  floatx4 acc[4][2];
  #pragma unroll
  for (int i = 0; i < 4; ++i)
    #pragma unroll
    for (int j = 0; j < 2; ++j)
      acc[i][j] = (floatx4){0.f, 0.f, 0.f, 0.f};

  for (int k0 = 0; k0 < DIN; k0 += BK) {
    __syncthreads();
    #pragma unroll
    for (int s4 = 0; s4 < 2; ++s4) glds16(bG[s4] + k0, bL[s4]);
    #pragma unroll
    for (int s4 = 0; s4 < 4; ++s4) glds16(aG[s4] + k0, aL[s4]);
    __syncthreads();
    #pragma unroll
    for (int h = 0; h < 2; ++h) {
      short8 af[4], bf[2];
      #pragma unroll
      for (int i = 0; i < 4; ++i) af[i] = *(const short8*)(lA + aOff[i][h]);
      #pragma unroll
      for (int j = 0; j < 2; ++j) bf[j] = *(const short8*)(lB + bOff[j][h]);
      // SWAPPED: D[p][c] = sum_k Wt[n-frag p][k] * A[m-frag c][k]
      #pragma unroll
      for (int i = 0; i < 4; ++i)
        #pragma unroll
        for (int j = 0; j < 2; ++j)
          acc[i][j] = __builtin_amdgcn_mfma_f32_16x16x32_bf16(bf[j], af[i], acc[i][j], 0, 0, 0);
    }
  }

  if (tid < BM) tokS[tid] = tpad[arow0 + tid];
  __syncthreads();

  // n = nt*64 + wn*32 + j*16 + q*4 + r (regs contiguous in n); m = wm*64+i*16+lrow
  float bias[2][4];
  #pragma unroll
  for (int j = 0; j < 2; ++j) {
    int n = nt * BN + wn * 32 + j * 16 + q * 4;
    if (fp32) {
      floatx4 b4 = *(const floatx4*)((const float*)bv + e * DOUT + n);
      #pragma unroll
      for (int r = 0; r < 4; ++r) bias[j][r] = b4[r];
    } else {
      short4v b4 = *(const short4v*)((const short*)bv + e * DOUT + n);
      #pragma unroll
      for (int r = 0; r < 4; ++r) bias[j][r] = b2f((unsigned short)b4[r]);
    }
  }
  #pragma unroll
  for (int i = 0; i < 4; ++i) {
    int tok = tokS[wm * 64 + i * 16 + lrow];
    if (tok < 0) continue;
    size_t rowb = (size_t)tok * DOUT + nt * BN + wn * 32 + q * 4;
    #pragma unroll
    for (int j = 0; j < 2; ++j) {
      if (fp32) {
        floatx4 o;
        #pragma unroll
        for (int r = 0; r < 4; ++r) {
          float v = acc[i][j][r] + bias[j][r];
          o[r] = v > 0.f ? v : 0.f;
        }
        *(floatx4*)((float*)outv + rowb + j * 16) = o;
      } else {
        short4v o;
        #pragma unroll
        for (int r = 0; r < 4; ++r) {
          float v = acc[i][j][r] + bias[j][r];
          o[r] = f2b(v > 0.f ? v : 0.f);
        }
        *(short4v*)((short*)outv + rowb + j * 16) = o;
      }
    }
  }
}

// ---- correct-but-slow fallback if ws too small
__global__ void k_fallback(const void* __restrict__ xv, const int* __restrict__ idxs,
                           const void* __restrict__ Wv, const void* __restrict__ bv,
                           void* __restrict__ outv) {
  __shared__ float xrow[DIN];
  __shared__ int sflag;
  int t = blockIdx.x;
  int e = idxs[t];
  if (threadIdx.x == 0) {
    const unsigned short* u = (const unsigned short*)xv;
    int f = 0;
    for (int i = 0; i < 256; ++i) { int ex = (u[i] >> 7) & 0xFF; if (ex >= 0xC0) f = 1; }
    sflag = f;
  }
  __syncthreads();
  int fp32 = sflag;
  for (int i = threadIdx.x; i < DIN; i += 256)
    xrow[i] = fp32 ? ((const float*)xv)[(size_t)t * DIN + i]
                   : b2f(((const unsigned short*)xv)[(size_t)t * DIN + i]);
  __syncthreads();
  float a[4] = {0.f, 0.f, 0.f, 0.f};
  for (int k = 0; k < DIN; ++k) {
    float xk = xrow[k];
    size_t wb = (size_t)e * DIN * DOUT + (size_t)k * DOUT + threadIdx.x;
    #pragma unroll
    for (int j = 0; j < 4; ++j) {
      float w = fp32 ? ((const float*)Wv)[wb + j * 256]
                     : b2f(((const unsigned short*)Wv)[wb + j * 256]);
      a[j] += xk * w;
    }
  }
  #pragma unroll
  for (int j = 0; j < 4; ++j) {
    int n = threadIdx.x + j * 256;
    float bias = fp32 ? ((const float*)bv)[e * DOUT + n]
                      : b2f(((const unsigned short*)bv)[e * DOUT + n]);
    float v = a[j] + bias;
    v = v > 0.f ? v : 0.f;
    size_t o = (size_t)t * DOUT + n;
    if (fp32) ((float*)outv)[o] = v;
    else      ((short*)outv)[o] = f2b(v);
  }
}

extern "C" void kernel_launch(void* const* d_in, const int* in_sizes, int n_in,
                              void* d_out, int out_size, void* d_ws, size_t ws_size,
                              hipStream_t stream) {
  const void* x    = d_in[0];
  const int*  idxs = (const int*)d_in[1];
  const void* W    = d_in[2];
  const void* bias = d_in[3];

  if (ws_size < WS_NEED) {
    k_fallback<<<T_TOK, 256, 0, stream>>>(x, idxs, W, bias, d_out);
    return;
  }
  char* ws = (char*)d_ws;
  int* flag    = (int*)(ws + FLAG_OFF);
  int* ntiles  = (int*)(ws + NTILES_OFF);
  int* counts  = (int*)(ws + COUNTS_OFF);
  int* padoff  = (int*)(ws + PADOFF_OFF);
  int* bbase   = (int*)(ws + BB_OFF);
  int4v* table = (int4v*)(ws + TABLE_OFF);
  int* tpad    = (int*)(ws + TPAD_OFF);
  short* Wt    = (short*)(ws + WT_OFF);
  short* Aperm = (short*)(ws + APERM_OFF);

  k_prep<<<1, 1024, 0, stream>>>((const unsigned short*)x, idxs, flag, counts,
                                 padoff, ntiles, table, bbase, tpad);
  k_scatter<<<T_TOK / 256, 256, 0, stream>>>(idxs, bbase, tpad);
  k_stage<<<TRANS_BLOCKS + GATHER_BLOCKS, 256, 0, stream>>>(
      W, Wt, x, Aperm, padoff, tpad, flag);
  k_gemm<<<8 * 16 * TPX, 256, 0, stream>>>(Aperm, bias, Wt, tpad, ntiles, table, flag, d_out);
}